// Round 11
// baseline (253.420 us; speedup 1.0000x reference)
//
#include <hip/hip_runtime.h>
#include <hip/hip_bf16.h>
#include <cstdint>

// Pipeline (all bf16 MFMA, fp32 accum):
//   cvt x7 -> gemm1(qkv) -> transpose_v -> attn(flash, LDS-staged K/V, no-max exp2)
//   -> gemm2(split-K x2, bf16 partials) -> ln_sum1(+src) -> gemm3(relu)
//   -> gemm4(split-K x2, bf16 partials) -> ln_sum2(+x)
// Round-11: attn = round-8 per-wave shape (16 q-rows/wave, 1024 blocks, 4 waves/SIMD)
// + round-10 block-level double-buffered K/V staging. 40KB LDS -> 4 blocks/CU.
// Occupancy was the limiter (18%, 2 waves/SIMD; VALU 33%/MFMA 22% both unsaturated).
// GEMMs/LN/cvt byte-identical to round 10 (proven under replay).

using bf16 = __hip_bfloat16;
typedef __attribute__((ext_vector_type(8))) __bf16 bf16x8;
typedef __attribute__((ext_vector_type(4))) __bf16 bf16x4;
typedef __attribute__((ext_vector_type(4))) float f32x4;

__device__ __forceinline__ void gload_lds16(const void* g, void* l) {
    auto gp = (const __attribute__((address_space(1))) void*)(uintptr_t)g;
    auto lp = (__attribute__((address_space(3))) void*)(uint32_t)(uintptr_t)l;
    __builtin_amdgcn_global_load_lds(gp, lp, 16, 0, 0);
}

// raw v_exp_f32 (1 instr) — scores are small/finite, no guard path needed
__device__ __forceinline__ float fast_exp2(float x) {
#if __has_builtin(__builtin_amdgcn_exp2f)
    return __builtin_amdgcn_exp2f(x);
#else
    float r;
    asm("v_exp_f32 %0, %1" : "=v"(r) : "v"(x));
    return r;
#endif
}

// 2-instr f32->bf16 (round-to-nearest). Inputs finite; bias far below threshold.
__device__ __forceinline__ bf16 bf16_rn(float x) {
    uint32_t u = __builtin_bit_cast(uint32_t, x);
    uint16_t h = (uint16_t)((u + 0x8000u) >> 16);
    return __builtin_bit_cast(bf16, h);
}

__device__ __forceinline__ float bf2f(__bf16 x) {
    return (float)x;
}

// ---------------- GEMM: C[M,N] = A[M,K] * B[N,K]^T (+bias, epilogue) ----------------
// EPI 0: qkv -> bf16, cols < 1024 scaled by d^-0.5 * log2(e)
// EPI 2: bf16 out = relu(acc + bias)
// EPI 3: split-K partial (gridDim.z=2): z half operates on K columns [z*K, z*K+K)
//        of A/B (row stride lda), writes bf16 partial to Cb + z*M*N; z=0 adds bias.
template <int EPI>
__global__ __launch_bounds__(256, 2) void gemm_bt(
    const bf16* __restrict__ A, const bf16* __restrict__ B,
    const float* __restrict__ bias, bf16* __restrict__ Cb,
    int M, int N, int K, int lda) {
    __shared__ alignas(16) bf16 As[128 * 32];
    __shared__ alignas(16) bf16 Bs[128 * 32];

    const int tid = threadIdx.x;
    const int wid = tid >> 6;
    const int lane = tid & 63;
    const int g = lane >> 4;
    const int li = lane & 15;

    if (EPI == 3) {
        const int zo = blockIdx.z * K;
        A += zo;
        B += zo;
    }

    // XCD-aware bijective swizzle (all grids here have nwg % 8 == 0)
    int wg = blockIdx.y * gridDim.x + blockIdx.x;
    const int nwg = gridDim.x * gridDim.y;
    const int cpx = nwg >> 3;
    wg = (wg & 7) * cpx + (wg >> 3);
    const int bx = wg % (int)gridDim.x;
    const int by = wg / (int)gridDim.x;

    const int row0 = by * 128;
    const int col0 = bx * 128;
    const int wr = (wid >> 1) * 64;
    const int wc = (wid & 1) * 64;

    const int c0 = wid, c1 = wid + 4;
    const int srow = lane >> 2;
    const int scol = (lane & 3) * 8;

    const bf16* Ag0 = A + (size_t)(row0 + c0 * 16 + srow) * lda + scol;
    const bf16* Ag1 = A + (size_t)(row0 + c1 * 16 + srow) * lda + scol;
    const bf16* Bg0 = B + (size_t)(col0 + c0 * 16 + srow) * lda + scol;
    const bf16* Bg1 = B + (size_t)(col0 + c1 * 16 + srow) * lda + scol;

    bf16* lA0 = &As[c0 * 512];
    bf16* lA1 = &As[c1 * 512];
    bf16* lB0 = &Bs[c0 * 512];
    bf16* lB1 = &Bs[c1 * 512];

    f32x4 acc[4][4];
#pragma unroll
    for (int i = 0; i < 4; ++i)
#pragma unroll
        for (int j = 0; j < 4; ++j) acc[i][j] = (f32x4){0.f, 0.f, 0.f, 0.f};

    for (int k0 = 0; k0 < K; k0 += 32) {
        gload_lds16(Ag0 + k0, lA0);
        gload_lds16(Ag1 + k0, lA1);
        gload_lds16(Bg0 + k0, lB0);
        gload_lds16(Bg1 + k0, lB1);
        __syncthreads();

        bf16x8 af[4], bfr[4];
#pragma unroll
        for (int i = 0; i < 4; ++i) {
            af[i] = *(const bf16x8*)&As[(wr + i * 16 + li) * 32 + g * 8];
            bfr[i] = *(const bf16x8*)&Bs[(wc + i * 16 + li) * 32 + g * 8];
        }
#pragma unroll
        for (int i = 0; i < 4; ++i)
#pragma unroll
            for (int j = 0; j < 4; ++j)
                acc[i][j] = __builtin_amdgcn_mfma_f32_16x16x32_bf16(af[i], bfr[j], acc[i][j], 0, 0, 0);
        __syncthreads();
    }

#pragma unroll
    for (int i = 0; i < 4; ++i) {
#pragma unroll
        for (int j = 0; j < 4; ++j) {
            const int col = col0 + wc + j * 16 + li;
            const float bv = (EPI == 3 && blockIdx.z != 0) ? 0.f : bias[col];
#pragma unroll
            for (int r = 0; r < 4; ++r) {
                const int row = row0 + wr + i * 16 + g * 4 + r;
                const size_t idx = (size_t)row * N + col;
                float v = acc[i][j][r] + bv;
                if (EPI == 0) {
                    if (col < 1024) v *= 0.18033688011112042f;  // d^-0.5 * log2(e)
                    Cb[idx] = bf16_rn(v);
                } else if (EPI == 2) {
                    Cb[idx] = bf16_rn(v > 0.f ? v : 0.f);
                } else {  // EPI == 3
                    Cb[(size_t)blockIdx.z * ((size_t)M * N) + idx] = bf16_rn(v);
                }
            }
        }
    }
}

// ---------------- V transpose: VT[(b*16+h)*64 + d][s] for s in [0,2080) ----------------
__global__ __launch_bounds__(256) void transpose_v(const bf16* __restrict__ qkv,
                                                   const bf16* __restrict__ mv,
                                                   bf16* __restrict__ vt) {
    __shared__ bf16 tile[64][72];
    const int t = blockIdx.x;  // 0..32 (32 = mem-token tile, 32 rows)
    const int h = blockIdx.y;
    const int b = blockIdx.z;
    const int tid = threadIdx.x;
    const int r = tid >> 2;
    const int c = (tid & 3) * 16;
    const int s0 = t * 64;
    if (t < 32) {
        const bf16* p = qkv + (size_t)((s0 + r) * 2 + b) * 3072 + 2048 + h * 64 + c;
        *(bf16x8*)&tile[r][c] = *(const bf16x8*)p;
        *(bf16x8*)&tile[r][c + 8] = *(const bf16x8*)(p + 8);
    } else if (r < 32) {
        const bf16* p = mv + (size_t)r * 1024 + h * 64 + c;
        *(bf16x8*)&tile[r][c] = *(const bf16x8*)p;
        *(bf16x8*)&tile[r][c + 8] = *(const bf16x8*)(p + 8);
    }
    __syncthreads();
    const int d = tid >> 2;
    const int sc = (tid & 3) * 16;
    const int smax = (t < 32) ? 64 : 32;
    if (sc < smax) {
        bf16 tmp[16];
#pragma unroll
        for (int j = 0; j < 16; ++j) tmp[j] = tile[sc + j][d];
        bf16* q = vt + (size_t)((b * 16 + h) * 64 + d) * 2080 + s0 + sc;
        *(bf16x8*)q = *(const bf16x8*)&tmp[0];
        *(bf16x8*)(q + 8) = *(const bf16x8*)&tmp[8];
    }
}

// ---------------- flash attention (no-max exp2 softmax, LDS-staged K/V) ----------------
// Block = 4 waves x 16 q-rows = 64 rows. Grid (h, qtile, b) = (16, 32, 2) = 1024 blocks
// -> 4 blocks/CU, 16 waves/CU (4/SIMD). x=16 % 8 == 0 -> all blocks of head h share
// XCD h%8, K/V L2-resident. K/V tiles staged once per block, double-buffered (32KB);
// Plds 8KB -> 40KB total, fits 4 blocks/CU.
__global__ __launch_bounds__(256, 4) void attn_kernel(
    const bf16* __restrict__ qkv, const bf16* __restrict__ mk,
    const bf16* __restrict__ vt, bf16* __restrict__ ctx) {
    __shared__ alignas(16) bf16 Kst[2][64 * 64];
    __shared__ alignas(16) bf16 Vst[2][64 * 64];
    __shared__ alignas(16) bf16 Plds[4][16 * 64];

    const int tid = threadIdx.x;
    const int wid = tid >> 6;
    const int lane = tid & 63;
    const int g = lane >> 4;
    const int li = lane & 15;

    const int h = blockIdx.x;
    const int b = blockIdx.z;
    const int q0 = blockIdx.y * 64 + wid * 16;

    bf16* pl = &Plds[wid][0];
    const bf16* vth = vt + (size_t)((b * 16 + h) * 64) * 2080;

    const int srow8 = lane >> 3;           // row & 7
    const int sslot = (lane & 7) ^ srow8;  // swizzled 16B slot in the row

#define STAGE_KV(buf, t)                                                                       \
    {                                                                                          \
        const int _s0 = (t) * 64;                                                              \
        _Pragma("unroll") for (int j = 0; j < 2; ++j) {                                        \
            const int rw = (wid * 2 + j) * 8 + srow8;                                          \
            gload_lds16(qkv + (size_t)((_s0 + rw) * 2 + b) * 3072 + 1024 + h * 64 + sslot * 8, \
                        &Kst[buf][(wid * 2 + j) * 512]);                                       \
            gload_lds16(vth + (size_t)rw * 2080 + _s0 + sslot * 8,                             \
                        &Vst[buf][(wid * 2 + j) * 512]);                                       \
        }                                                                                      \
    }

    bf16x8 qf[2];
#pragma unroll
    for (int kd = 0; kd < 2; ++kd)
        qf[kd] = *(const bf16x8*)(qkv + (size_t)((q0 + li) * 2 + b) * 3072 + h * 64 + kd * 32 +
                                  g * 8);

    f32x4 o[4];
    float lrow[4];
#pragma unroll
    for (int ni = 0; ni < 4; ++ni) o[ni] = (f32x4){0.f, 0.f, 0.f, 0.f};
#pragma unroll
    for (int r = 0; r < 4; ++r) lrow[r] = 0.f;

    STAGE_KV(0, 0);

    for (int t = 0; t < 32; ++t) {
        const int cur = t & 1;
        __syncthreads();  // buf[cur] staged (compiler drains vmcnt) & prior readers done
        if (t < 31) STAGE_KV(cur ^ 1, t + 1);

        // K fragments from LDS (swizzled slots; 2-way banks = free)
        bf16x8 kf[4][2];
#pragma unroll
        for (int si = 0; si < 4; ++si)
#pragma unroll
            for (int kd = 0; kd < 2; ++kd)
                kf[si][kd] = *(const bf16x8*)&Kst[cur][(si * 16 + li) * 64 +
                                                       (((kd * 4 + g) ^ (li & 7)) * 8)];

        f32x4 sa[4];
#pragma unroll
        for (int si = 0; si < 4; ++si) sa[si] = (f32x4){0.f, 0.f, 0.f, 0.f};
#pragma unroll
        for (int si = 0; si < 4; ++si)
#pragma unroll
            for (int kd = 0; kd < 2; ++kd)
                sa[si] = __builtin_amdgcn_mfma_f32_16x16x32_bf16(qf[kd], kf[si][kd], sa[si], 0, 0, 0);

        // V fragments from LDS — issue while softmax runs
        bf16x8 vf[2][4];
#pragma unroll
        for (int sblk = 0; sblk < 2; ++sblk)
#pragma unroll
            for (int ni = 0; ni < 4; ++ni)
                vf[sblk][ni] = *(const bf16x8*)&Vst[cur][(ni * 16 + li) * 64 +
                                                         (((sblk * 4 + g) ^ (li & 7)) * 8)];

        // exp2 (no max subtraction), per-lane partial row sums
#pragma unroll
        for (int r = 0; r < 4; ++r) {
            float ps = 0.f;
#pragma unroll
            for (int si = 0; si < 4; ++si) {
                const float p = fast_exp2(sa[si][r]);
                sa[si][r] = p;
                ps += p;
            }
            lrow[r] += ps;
        }

        // P -> per-wave swizzled LDS (row = g*4+r, so (row>>2)&3 == g)
#pragma unroll
        for (int si = 0; si < 4; ++si)
#pragma unroll
            for (int r = 0; r < 4; ++r) {
                const int row = g * 4 + r;
                const int col = (si * 16 + li) ^ (g << 4);
                pl[row * 64 + col] = bf16_rn(sa[si][r]);
            }

        asm volatile("s_waitcnt lgkmcnt(0)" ::: "memory");
        __builtin_amdgcn_sched_barrier(0);  // rule #18: pin ops after the wait

        bf16x8 pa[2];
#pragma unroll
        for (int sblk = 0; sblk < 2; ++sblk) {
            const int e = (sblk * 32 + g * 8) ^ (((li >> 2) & 3) << 4);
            pa[sblk] = *(const bf16x8*)&pl[li * 64 + e];
        }

#pragma unroll
        for (int sblk = 0; sblk < 2; ++sblk)
#pragma unroll
            for (int ni = 0; ni < 4; ++ni)
                o[ni] = __builtin_amdgcn_mfma_f32_16x16x32_bf16(pa[sblk], vf[sblk][ni], o[ni], 0, 0, 0);
    }

    // ---- tail: 32 memory tokens (global reads, no LDS staging) ----
    {
        bf16x8 kf[2][2];
#pragma unroll
        for (int si = 0; si < 2; ++si)
#pragma unroll
            for (int kd = 0; kd < 2; ++kd)
                kf[si][kd] = *(const bf16x8*)(mk + (size_t)(si * 16 + li) * 1024 + h * 64 +
                                              kd * 32 + g * 8);
        bf16x8 vf[4];
#pragma unroll
        for (int ni = 0; ni < 4; ++ni)
            vf[ni] = *(const bf16x8*)(vth + (size_t)(ni * 16 + li) * 2080 + 2048 + g * 8);

        f32x4 sa[2];
#pragma unroll
        for (int si = 0; si < 2; ++si) sa[si] = (f32x4){0.f, 0.f, 0.f, 0.f};
#pragma unroll
        for (int si = 0; si < 2; ++si)
#pragma unroll
            for (int kd = 0; kd < 2; ++kd)
                sa[si] = __builtin_amdgcn_mfma_f32_16x16x32_bf16(qf[kd], kf[si][kd], sa[si], 0, 0, 0);
#pragma unroll
        for (int r = 0; r < 4; ++r) {
            float ps = 0.f;
#pragma unroll
            for (int si = 0; si < 2; ++si) {
                const float p = fast_exp2(sa[si][r]);
                sa[si][r] = p;
                ps += p;
            }
            lrow[r] += ps;
        }
#pragma unroll
        for (int si = 0; si < 2; ++si)
#pragma unroll
            for (int r = 0; r < 4; ++r) {
                const int row = g * 4 + r;
                const int col = (si * 16 + li) ^ (g << 4);
                pl[row * 64 + col] = bf16_rn(sa[si][r]);
            }

        asm volatile("s_waitcnt lgkmcnt(0)" ::: "memory");
        __builtin_amdgcn_sched_barrier(0);

        bf16x8 pa;
        {
            const int e = (g * 8) ^ (((li >> 2) & 3) << 4);
            pa = *(const bf16x8*)&pl[li * 64 + e];
        }
#pragma unroll
        for (int ni = 0; ni < 4; ++ni)
            o[ni] = __builtin_amdgcn_mfma_f32_16x16x32_bf16(pa, vf[ni], o[ni], 0, 0, 0);
    }

    // epilogue: one shuffle-reduce of the deferred row sums, then scatter
#pragma unroll
    for (int r = 0; r < 4; ++r) {
        float s = lrow[r];
#pragma unroll
        for (int d = 1; d < 16; d <<= 1) s += __shfl_xor(s, d);
        const float inv = 1.f / s;
        const int trow = q0 + g * 4 + r;
#pragma unroll
        for (int ni = 0; ni < 4; ++ni)
            ctx[(size_t)(trow * 2 + b) * 1024 + h * 64 + ni * 16 + li] = bf16_rn(o[ni][r] * inv);
    }
#undef STAGE_KV
}

// ---------------- LayerNorm over rows of 1024: y = LN(p0 + p1 + xres) ----------------
// p0/p1: bf16 split-K partials (p0 carries the bias); xres: fp32 residual.
__global__ __launch_bounds__(256, 4) void ln_sum_kernel(
    const bf16* __restrict__ p0, const bf16* __restrict__ p1, const float* __restrict__ xres,
    const float* __restrict__ gw, const float* __restrict__ bw,
    float* __restrict__ y, bf16* __restrict__ ybf) {
    const int row = blockIdx.x;
    const int tid = threadIdx.x;
    const size_t base = (size_t)row * 1024 + tid * 4;
    const bf16x4 a0 = *(const bf16x4*)(p0 + base);
    const bf16x4 a1 = *(const bf16x4*)(p1 + base);
    const float4 xr = ((const float4*)(xres + (size_t)row * 1024))[tid];
    float4 v;
    v.x = bf2f(a0[0]) + bf2f(a1[0]) + xr.x;
    v.y = bf2f(a0[1]) + bf2f(a1[1]) + xr.y;
    v.z = bf2f(a0[2]) + bf2f(a1[2]) + xr.z;
    v.w = bf2f(a0[3]) + bf2f(a1[3]) + xr.w;

    float s = v.x + v.y + v.z + v.w;
    float s2 = v.x * v.x + v.y * v.y + v.z * v.z + v.w * v.w;
#pragma unroll
    for (int d = 1; d < 64; d <<= 1) {
        s += __shfl_xor(s, d);
        s2 += __shfl_xor(s2, d);
    }
    __shared__ float red[8];
    const int wid = tid >> 6, lane = tid & 63;
    if (lane == 0) { red[wid] = s; red[4 + wid] = s2; }
    __syncthreads();
    s = red[0] + red[1] + red[2] + red[3];
    s2 = red[4] + red[5] + red[6] + red[7];
    const float mu = s * (1.f / 1024.f);
    const float var = s2 * (1.f / 1024.f) - mu * mu;
    const float rstd = rsqrtf(var + 1e-5f);
    const float4 gv = ((const float4*)gw)[tid];
    const float4 bv = ((const float4*)bw)[tid];
    float4 out;
    out.x = (v.x - mu) * rstd * gv.x + bv.x;
    out.y = (v.y - mu) * rstd * gv.y + bv.y;
    out.z = (v.z - mu) * rstd * gv.z + bv.z;
    out.w = (v.w - mu) * rstd * gv.w + bv.w;
    if (y) ((float4*)(y + (size_t)row * 1024))[tid] = out;
    if (ybf) {
        bf16* yb = ybf + base;
        yb[0] = bf16_rn(out.x);
        yb[1] = bf16_rn(out.y);
        yb[2] = bf16_rn(out.z);
        yb[3] = bf16_rn(out.w);
    }
}

// ---------------- fp32 -> bf16 (optionally scaled) ----------------
__global__ void cvt_kernel(const float* __restrict__ in, bf16* __restrict__ out, float scale,
                           int n4) {
    const int i = blockIdx.x * 256 + threadIdx.x;
    if (i >= n4) return;
    const float4 v = ((const float4*)in)[i];
    bf16* op = out + (size_t)i * 4;
    op[0] = bf16_rn(v.x * scale);
    op[1] = bf16_rn(v.y * scale);
    op[2] = bf16_rn(v.z * scale);
    op[3] = bf16_rn(v.w * scale);
}

extern "C" void kernel_launch(void* const* d_in, const int* in_sizes, int n_in, void* d_out,
                              int out_size, void* d_ws, size_t ws_size, hipStream_t stream) {
    const float* src = (const float*)d_in[0];
    const float* inproj_w = (const float*)d_in[1];
    const float* inproj_b = (const float*)d_in[2];
    const float* outw = (const float*)d_in[3];
    const float* outb = (const float*)d_in[4];
    const float* memk = (const float*)d_in[5];
    const float* memv = (const float*)d_in[6];
    const float* w1 = (const float*)d_in[7];
    const float* b1 = (const float*)d_in[8];
    const float* w2 = (const float*)d_in[9];
    const float* b2 = (const float*)d_in[10];
    const float* ln1g = (const float*)d_in[11];
    const float* ln1b = (const float*)d_in[12];
    const float* ln2g = (const float*)d_in[13];
    const float* ln2b = (const float*)d_in[14];

    char* ws = (char*)d_ws;
    const size_t MB = 1024 * 1024;
    bf16* w_inproj_bf = (bf16*)(ws + 0);          // 6 MB   [gemm1]
    bf16* w_out_bf = (bf16*)(ws + 6 * MB);        // 2 MB   [gemm2]
    bf16* w1_bf = (bf16*)(ws + 8 * MB);           // 8 MB   [gemm3]
    bf16* w2_bf = (bf16*)(ws + 16 * MB);          // 8 MB   [gemm4]
    bf16* mk_bf = (bf16*)(ws + 24 * MB);          // 64 KB  [attn]
    bf16* mv_bf = (bf16*)(ws + 24 * MB + 65536);  // 64 KB  [transpose_v]
    bf16* src_bf = (bf16*)(ws + 25 * MB);         // 8 MB   [gemm1]
    bf16* ctx_bf = src_bf;                        // reuse  [attn -> gemm2]
    bf16* qkv_bf = (bf16*)(ws + 33 * MB);         // 24 MB  [gemm1 -> attn]
    bf16* h_bf = qkv_bf;                          // 32 MB reuse [gemm3 -> gemm4]
    bf16* vt_bf = (bf16*)(ws + 65 * MB);          // 8.5 MB [transpose_v -> attn]
    bf16* g2p = vt_bf;                            // reuse  [split-K partials; vt dead by then]
    float* x_f = (float*)(ws + 81 * MB);          // 16 MB  [ln1 -> ln2 residual]
    bf16* x_bf = (bf16*)(ws + 97 * MB);           // 8 MB   [ln1 -> gemm3]
    float* outp = (float*)d_out;
    // split-K partials: base g2p (65..81 MB region, two contiguous 8MB slots).
    // gemm2 partials consumed by ln_sum1 before gemm4 reuses the same region.

    auto cvt = [&](const float* in, bf16* out, float scale, int n) {
        int n4 = n / 4;
        cvt_kernel<<<dim3((n4 + 255) / 256), dim3(256), 0, stream>>>(in, out, scale, n4);
    };
    cvt(src, src_bf, 1.f, 4096 * 1024);
    cvt(inproj_w, w_inproj_bf, 1.f, 3072 * 1024);
    cvt(outw, w_out_bf, 1.f, 1024 * 1024);
    cvt(w1, w1_bf, 1.f, 4096 * 1024);
    cvt(w2, w2_bf, 1.f, 4096 * 1024);
    cvt(memk, mk_bf, 8.f, 32 * 1024);                 // * d^0.5 (log2e rides on q)
    cvt(memv, mv_bf, 5.656854249492381f, 32 * 1024);  // * M^0.5

    // qkv = src @ in_proj_w^T + b  (q scaled by d^-0.5*log2e)
    gemm_bt<0><<<dim3(3072 / 128, 4096 / 128), 256, 0, stream>>>(
        src_bf, w_inproj_bf, inproj_b, qkv_bf, 4096, 3072, 1024, 1024);
    // VT = V^T (incl. mem tokens)
    transpose_v<<<dim3(33, 16, 2), 256, 0, stream>>>(qkv_bf, mv_bf, vt_bf);
    // ctx = softmax(q k^T) v    (grid: x=head for XCD L2 locality; 1024 blocks)
    attn_kernel<<<dim3(16, 32, 2), 256, 0, stream>>>(qkv_bf, mk_bf, vt_bf, ctx_bf);
    // gemm2 split-K x2: partials = ctx @ out_w^T (+out_b on z=0), K=512 each
    gemm_bt<3><<<dim3(1024 / 128, 4096 / 128, 2), 256, 0, stream>>>(
        ctx_bf, w_out_bf, outb, g2p, 4096, 1024, 512, 1024);
    // x = LN1(p0 + p1 + src)
    ln_sum_kernel<<<dim3(4096), 256, 0, stream>>>(g2p, g2p + (size_t)4096 * 1024, src, ln1g, ln1b,
                                                  x_f, x_bf);
    // h = relu(x @ w1^T + b1)
    gemm_bt<2><<<dim3(4096 / 128, 4096 / 128), 256, 0, stream>>>(
        x_bf, w1_bf, b1, h_bf, 4096, 4096, 1024, 1024);
    // gemm4 split-K x2: partials = h @ w2^T (+b2 on z=0), K=2048 each
    gemm_bt<3><<<dim3(1024 / 128, 4096 / 128, 2), 256, 0, stream>>>(
        h_bf, w2_bf, b2, g2p, 4096, 1024, 2048, 4096);
    // out = LN2(p0 + p1 + x)
    ln_sum_kernel<<<dim3(4096), 256, 0, stream>>>(g2p, g2p + (size_t)4096 * 1024, x_f, ln2g, ln2b,
                                                  outp, nullptr);
}

// Round 12
// 236.231 us; speedup vs baseline: 1.0728x; 1.0728x over previous
//
#include <hip/hip_runtime.h>
#include <hip/hip_bf16.h>
#include <cstdint>

// Pipeline (all bf16 MFMA, fp32 accum):
//   cvt_all -> gemm1(qkv) -> transpose_v -> attn(flash, LDS-staged K/V, no-max exp2)
//   -> gemm2(split-K x2, bf16 partials) -> ln_sum1(+src) -> gemm3(relu)
//   -> gemm4(split-K x2, bf16 partials) -> ln_sum2(+x)
// Round-12: attn reverted to the round-10 kernel (63 us proven; round-11's 16-row
// waves doubled staging/L2 traffic and regressed) + T5 s_setprio around MFMA
// clusters (measured +4-7% on decoupled attn blocks). 7 cvt launches fused into 1.
// GEMMs/LN byte-identical to round 10 (proven under replay).

using bf16 = __hip_bfloat16;
typedef __attribute__((ext_vector_type(8))) __bf16 bf16x8;
typedef __attribute__((ext_vector_type(4))) __bf16 bf16x4;
typedef __attribute__((ext_vector_type(4))) float f32x4;

__device__ __forceinline__ void gload_lds16(const void* g, void* l) {
    auto gp = (const __attribute__((address_space(1))) void*)(uintptr_t)g;
    auto lp = (__attribute__((address_space(3))) void*)(uint32_t)(uintptr_t)l;
    __builtin_amdgcn_global_load_lds(gp, lp, 16, 0, 0);
}

// raw v_exp_f32 (1 instr) — scores are small/finite, no guard path needed
__device__ __forceinline__ float fast_exp2(float x) {
#if __has_builtin(__builtin_amdgcn_exp2f)
    return __builtin_amdgcn_exp2f(x);
#else
    float r;
    asm("v_exp_f32 %0, %1" : "=v"(r) : "v"(x));
    return r;
#endif
}

// 2-instr f32->bf16 (round-to-nearest). Inputs finite; bias far below threshold.
__device__ __forceinline__ bf16 bf16_rn(float x) {
    uint32_t u = __builtin_bit_cast(uint32_t, x);
    uint16_t h = (uint16_t)((u + 0x8000u) >> 16);
    return __builtin_bit_cast(bf16, h);
}

__device__ __forceinline__ float bf2f(__bf16 x) {
    return (float)x;
}

// ---------------- GEMM: C[M,N] = A[M,K] * B[N,K]^T (+bias, epilogue) ----------------
// EPI 0: qkv -> bf16, cols < 1024 scaled by d^-0.5 * log2(e)
// EPI 2: bf16 out = relu(acc + bias)
// EPI 3: split-K partial (gridDim.z=2): z half operates on K columns [z*K, z*K+K)
//        of A/B (row stride lda), writes bf16 partial to Cb + z*M*N; z=0 adds bias.
template <int EPI>
__global__ __launch_bounds__(256, 2) void gemm_bt(
    const bf16* __restrict__ A, const bf16* __restrict__ B,
    const float* __restrict__ bias, bf16* __restrict__ Cb,
    int M, int N, int K, int lda) {
    __shared__ alignas(16) bf16 As[128 * 32];
    __shared__ alignas(16) bf16 Bs[128 * 32];

    const int tid = threadIdx.x;
    const int wid = tid >> 6;
    const int lane = tid & 63;
    const int g = lane >> 4;
    const int li = lane & 15;

    if (EPI == 3) {
        const int zo = blockIdx.z * K;
        A += zo;
        B += zo;
    }

    // XCD-aware bijective swizzle (all grids here have nwg % 8 == 0)
    int wg = blockIdx.y * gridDim.x + blockIdx.x;
    const int nwg = gridDim.x * gridDim.y;
    const int cpx = nwg >> 3;
    wg = (wg & 7) * cpx + (wg >> 3);
    const int bx = wg % (int)gridDim.x;
    const int by = wg / (int)gridDim.x;

    const int row0 = by * 128;
    const int col0 = bx * 128;
    const int wr = (wid >> 1) * 64;
    const int wc = (wid & 1) * 64;

    const int c0 = wid, c1 = wid + 4;
    const int srow = lane >> 2;
    const int scol = (lane & 3) * 8;

    const bf16* Ag0 = A + (size_t)(row0 + c0 * 16 + srow) * lda + scol;
    const bf16* Ag1 = A + (size_t)(row0 + c1 * 16 + srow) * lda + scol;
    const bf16* Bg0 = B + (size_t)(col0 + c0 * 16 + srow) * lda + scol;
    const bf16* Bg1 = B + (size_t)(col0 + c1 * 16 + srow) * lda + scol;

    bf16* lA0 = &As[c0 * 512];
    bf16* lA1 = &As[c1 * 512];
    bf16* lB0 = &Bs[c0 * 512];
    bf16* lB1 = &Bs[c1 * 512];

    f32x4 acc[4][4];
#pragma unroll
    for (int i = 0; i < 4; ++i)
#pragma unroll
        for (int j = 0; j < 4; ++j) acc[i][j] = (f32x4){0.f, 0.f, 0.f, 0.f};

    for (int k0 = 0; k0 < K; k0 += 32) {
        gload_lds16(Ag0 + k0, lA0);
        gload_lds16(Ag1 + k0, lA1);
        gload_lds16(Bg0 + k0, lB0);
        gload_lds16(Bg1 + k0, lB1);
        __syncthreads();

        bf16x8 af[4], bfr[4];
#pragma unroll
        for (int i = 0; i < 4; ++i) {
            af[i] = *(const bf16x8*)&As[(wr + i * 16 + li) * 32 + g * 8];
            bfr[i] = *(const bf16x8*)&Bs[(wc + i * 16 + li) * 32 + g * 8];
        }
#pragma unroll
        for (int i = 0; i < 4; ++i)
#pragma unroll
            for (int j = 0; j < 4; ++j)
                acc[i][j] = __builtin_amdgcn_mfma_f32_16x16x32_bf16(af[i], bfr[j], acc[i][j], 0, 0, 0);
        __syncthreads();
    }

#pragma unroll
    for (int i = 0; i < 4; ++i) {
#pragma unroll
        for (int j = 0; j < 4; ++j) {
            const int col = col0 + wc + j * 16 + li;
            const float bv = (EPI == 3 && blockIdx.z != 0) ? 0.f : bias[col];
#pragma unroll
            for (int r = 0; r < 4; ++r) {
                const int row = row0 + wr + i * 16 + g * 4 + r;
                const size_t idx = (size_t)row * N + col;
                float v = acc[i][j][r] + bv;
                if (EPI == 0) {
                    if (col < 1024) v *= 0.18033688011112042f;  // d^-0.5 * log2(e)
                    Cb[idx] = bf16_rn(v);
                } else if (EPI == 2) {
                    Cb[idx] = bf16_rn(v > 0.f ? v : 0.f);
                } else {  // EPI == 3
                    Cb[(size_t)blockIdx.z * ((size_t)M * N) + idx] = bf16_rn(v);
                }
            }
        }
    }
}

// ---------------- V transpose: VT[(b*16+h)*64 + d][s] for s in [0,2080) ----------------
__global__ __launch_bounds__(256) void transpose_v(const bf16* __restrict__ qkv,
                                                   const bf16* __restrict__ mv,
                                                   bf16* __restrict__ vt) {
    __shared__ bf16 tile[64][72];
    const int t = blockIdx.x;  // 0..32 (32 = mem-token tile, 32 rows)
    const int h = blockIdx.y;
    const int b = blockIdx.z;
    const int tid = threadIdx.x;
    const int r = tid >> 2;
    const int c = (tid & 3) * 16;
    const int s0 = t * 64;
    if (t < 32) {
        const bf16* p = qkv + (size_t)((s0 + r) * 2 + b) * 3072 + 2048 + h * 64 + c;
        *(bf16x8*)&tile[r][c] = *(const bf16x8*)p;
        *(bf16x8*)&tile[r][c + 8] = *(const bf16x8*)(p + 8);
    } else if (r < 32) {
        const bf16* p = mv + (size_t)r * 1024 + h * 64 + c;
        *(bf16x8*)&tile[r][c] = *(const bf16x8*)p;
        *(bf16x8*)&tile[r][c + 8] = *(const bf16x8*)(p + 8);
    }
    __syncthreads();
    const int d = tid >> 2;
    const int sc = (tid & 3) * 16;
    const int smax = (t < 32) ? 64 : 32;
    if (sc < smax) {
        bf16 tmp[16];
#pragma unroll
        for (int j = 0; j < 16; ++j) tmp[j] = tile[sc + j][d];
        bf16* q = vt + (size_t)((b * 16 + h) * 64 + d) * 2080 + s0 + sc;
        *(bf16x8*)q = *(const bf16x8*)&tmp[0];
        *(bf16x8*)(q + 8) = *(const bf16x8*)&tmp[8];
    }
}

// ---------------- flash attention (no-max exp2 softmax, LDS-staged K/V) ----------------
// Round-10 kernel verbatim + s_setprio around MFMA clusters (T5).
// Block = 4 waves x 32 q-rows. Grid (h, qtile, b): x=16 % 8 == 0 -> all blocks of
// head h share XCD h%8, K/V L2-resident. K/V staged once per block, double-buffered.
__global__ __launch_bounds__(256, 2) void attn_kernel(
    const bf16* __restrict__ qkv, const bf16* __restrict__ mk,
    const bf16* __restrict__ vt, bf16* __restrict__ ctx) {
    __shared__ alignas(16) bf16 Kst[2][64 * 64];
    __shared__ alignas(16) bf16 Vst[2][64 * 64];
    __shared__ alignas(16) bf16 Plds[4][32 * 64];

    const int tid = threadIdx.x;
    const int wid = tid >> 6;
    const int lane = tid & 63;
    const int g = lane >> 4;
    const int li = lane & 15;

    const int h = blockIdx.x;
    const int b = blockIdx.z;
    const int q0 = blockIdx.y * 128 + wid * 32;

    bf16* pl = &Plds[wid][0];
    const bf16* vth = vt + (size_t)((b * 16 + h) * 64) * 2080;

    const int srow8 = lane >> 3;           // row & 7
    const int sslot = (lane & 7) ^ srow8;  // swizzled 16B slot in the row

#define STAGE_KV(buf, t)                                                                       \
    {                                                                                          \
        const int _s0 = (t) * 64;                                                              \
        _Pragma("unroll") for (int j = 0; j < 2; ++j) {                                        \
            const int rw = (wid * 2 + j) * 8 + srow8;                                          \
            gload_lds16(qkv + (size_t)((_s0 + rw) * 2 + b) * 3072 + 1024 + h * 64 + sslot * 8, \
                        &Kst[buf][(wid * 2 + j) * 512]);                                       \
            gload_lds16(vth + (size_t)rw * 2080 + _s0 + sslot * 8,                             \
                        &Vst[buf][(wid * 2 + j) * 512]);                                       \
        }                                                                                      \
    }

    bf16x8 qf[2][2];
#pragma unroll
    for (int mi = 0; mi < 2; ++mi)
#pragma unroll
        for (int kd = 0; kd < 2; ++kd)
            qf[mi][kd] = *(const bf16x8*)(qkv + (size_t)((q0 + mi * 16 + li) * 2 + b) * 3072 +
                                          h * 64 + kd * 32 + g * 8);

    f32x4 o[2][4];
    float lrow[2][4];
#pragma unroll
    for (int mi = 0; mi < 2; ++mi) {
#pragma unroll
        for (int ni = 0; ni < 4; ++ni) o[mi][ni] = (f32x4){0.f, 0.f, 0.f, 0.f};
#pragma unroll
        for (int r = 0; r < 4; ++r) lrow[mi][r] = 0.f;
    }

    STAGE_KV(0, 0);

    for (int t = 0; t < 32; ++t) {
        const int cur = t & 1;
        __syncthreads();  // buf[cur] staged (compiler drains vmcnt) & prior readers done
        if (t < 31) STAGE_KV(cur ^ 1, t + 1);

        bf16x8 kf[4][2];
#pragma unroll
        for (int si = 0; si < 4; ++si)
#pragma unroll
            for (int kd = 0; kd < 2; ++kd)
                kf[si][kd] = *(const bf16x8*)&Kst[cur][(si * 16 + li) * 64 +
                                                       (((kd * 4 + g) ^ (li & 7)) * 8)];

        f32x4 sa[2][4];
#pragma unroll
        for (int mi = 0; mi < 2; ++mi)
#pragma unroll
            for (int si = 0; si < 4; ++si) sa[mi][si] = (f32x4){0.f, 0.f, 0.f, 0.f};
        __builtin_amdgcn_s_setprio(1);
#pragma unroll
        for (int mi = 0; mi < 2; ++mi)
#pragma unroll
            for (int si = 0; si < 4; ++si)
#pragma unroll
                for (int kd = 0; kd < 2; ++kd)
                    sa[mi][si] = __builtin_amdgcn_mfma_f32_16x16x32_bf16(qf[mi][kd], kf[si][kd],
                                                                         sa[mi][si], 0, 0, 0);
        __builtin_amdgcn_s_setprio(0);

        bf16x8 vf[2][4];
#pragma unroll
        for (int sblk = 0; sblk < 2; ++sblk)
#pragma unroll
            for (int ni = 0; ni < 4; ++ni)
                vf[sblk][ni] = *(const bf16x8*)&Vst[cur][(ni * 16 + li) * 64 +
                                                         (((sblk * 4 + g) ^ (li & 7)) * 8)];

#pragma unroll
        for (int mi = 0; mi < 2; ++mi)
#pragma unroll
            for (int r = 0; r < 4; ++r) {
                float ps = 0.f;
#pragma unroll
                for (int si = 0; si < 4; ++si) {
                    const float p = fast_exp2(sa[mi][si][r]);
                    sa[mi][si][r] = p;
                    ps += p;
                }
                lrow[mi][r] += ps;
            }

#pragma unroll
        for (int mi = 0; mi < 2; ++mi)
#pragma unroll
            for (int si = 0; si < 4; ++si)
#pragma unroll
                for (int r = 0; r < 4; ++r) {
                    const int row = mi * 16 + g * 4 + r;
                    const int col = (si * 16 + li) ^ (((row >> 2) & 3) << 4);
                    pl[row * 64 + col] = bf16_rn(sa[mi][si][r]);
                }

        asm volatile("s_waitcnt lgkmcnt(0)" ::: "memory");
        __builtin_amdgcn_sched_barrier(0);  // rule #18: pin ops after the wait

        bf16x8 pa[2][2];
#pragma unroll
        for (int mi = 0; mi < 2; ++mi)
#pragma unroll
            for (int sblk = 0; sblk < 2; ++sblk) {
                const int row = mi * 16 + li;
                const int e = (sblk * 32 + g * 8) ^ (((row >> 2) & 3) << 4);
                pa[mi][sblk] = *(const bf16x8*)&pl[row * 64 + e];
            }

        __builtin_amdgcn_s_setprio(1);
#pragma unroll
        for (int sblk = 0; sblk < 2; ++sblk)
#pragma unroll
            for (int ni = 0; ni < 4; ++ni)
#pragma unroll
                for (int mi = 0; mi < 2; ++mi)
                    o[mi][ni] = __builtin_amdgcn_mfma_f32_16x16x32_bf16(pa[mi][sblk], vf[sblk][ni],
                                                                        o[mi][ni], 0, 0, 0);
        __builtin_amdgcn_s_setprio(0);
    }

    // ---- tail: 32 memory tokens (global reads, no LDS staging) ----
    {
        bf16x8 kf[2][2];
#pragma unroll
        for (int si = 0; si < 2; ++si)
#pragma unroll
            for (int kd = 0; kd < 2; ++kd)
                kf[si][kd] = *(const bf16x8*)(mk + (size_t)(si * 16 + li) * 1024 + h * 64 +
                                              kd * 32 + g * 8);
        bf16x8 vf[4];
#pragma unroll
        for (int ni = 0; ni < 4; ++ni)
            vf[ni] = *(const bf16x8*)(vth + (size_t)(ni * 16 + li) * 2080 + 2048 + g * 8);

        f32x4 sa[2][2];
#pragma unroll
        for (int mi = 0; mi < 2; ++mi)
#pragma unroll
            for (int si = 0; si < 2; ++si) sa[mi][si] = (f32x4){0.f, 0.f, 0.f, 0.f};
#pragma unroll
        for (int mi = 0; mi < 2; ++mi)
#pragma unroll
            for (int si = 0; si < 2; ++si)
#pragma unroll
                for (int kd = 0; kd < 2; ++kd)
                    sa[mi][si] = __builtin_amdgcn_mfma_f32_16x16x32_bf16(qf[mi][kd], kf[si][kd],
                                                                         sa[mi][si], 0, 0, 0);
#pragma unroll
        for (int mi = 0; mi < 2; ++mi)
#pragma unroll
            for (int r = 0; r < 4; ++r) {
                float ps = 0.f;
#pragma unroll
                for (int si = 0; si < 2; ++si) {
                    const float p = fast_exp2(sa[mi][si][r]);
                    sa[mi][si][r] = p;
                    ps += p;
                }
                lrow[mi][r] += ps;
            }
#pragma unroll
        for (int mi = 0; mi < 2; ++mi)
#pragma unroll
            for (int si = 0; si < 2; ++si)
#pragma unroll
                for (int r = 0; r < 4; ++r) {
                    const int row = mi * 16 + g * 4 + r;
                    const int col = (si * 16 + li) ^ (((row >> 2) & 3) << 4);
                    pl[row * 64 + col] = bf16_rn(sa[mi][si][r]);
                }

        asm volatile("s_waitcnt lgkmcnt(0)" ::: "memory");
        __builtin_amdgcn_sched_barrier(0);

        bf16x8 pa[2];
#pragma unroll
        for (int mi = 0; mi < 2; ++mi) {
            const int row = mi * 16 + li;
            const int e = (g * 8) ^ (((row >> 2) & 3) << 4);
            pa[mi] = *(const bf16x8*)&pl[row * 64 + e];
        }
#pragma unroll
        for (int ni = 0; ni < 4; ++ni)
#pragma unroll
            for (int mi = 0; mi < 2; ++mi)
                o[mi][ni] = __builtin_amdgcn_mfma_f32_16x16x32_bf16(pa[mi], vf[ni], o[mi][ni], 0, 0, 0);
    }

    // epilogue: one shuffle-reduce of the deferred row sums, then scatter
#pragma unroll
    for (int mi = 0; mi < 2; ++mi)
#pragma unroll
        for (int r = 0; r < 4; ++r) {
            float s = lrow[mi][r];
#pragma unroll
            for (int d = 1; d < 16; d <<= 1) s += __shfl_xor(s, d);
            const float inv = 1.f / s;
            const int trow = q0 + mi * 16 + g * 4 + r;
#pragma unroll
            for (int ni = 0; ni < 4; ++ni)
                ctx[(size_t)(trow * 2 + b) * 1024 + h * 64 + ni * 16 + li] =
                    bf16_rn(o[mi][ni][r] * inv);
        }
#undef STAGE_KV
}

// ---------------- LayerNorm over rows of 1024: y = LN(p0 + p1 + xres) ----------------
// p0/p1: bf16 split-K partials (p0 carries the bias); xres: fp32 residual.
__global__ __launch_bounds__(256, 4) void ln_sum_kernel(
    const bf16* __restrict__ p0, const bf16* __restrict__ p1, const float* __restrict__ xres,
    const float* __restrict__ gw, const float* __restrict__ bw,
    float* __restrict__ y, bf16* __restrict__ ybf) {
    const int row = blockIdx.x;
    const int tid = threadIdx.x;
    const size_t base = (size_t)row * 1024 + tid * 4;
    const bf16x4 a0 = *(const bf16x4*)(p0 + base);
    const bf16x4 a1 = *(const bf16x4*)(p1 + base);
    const float4 xr = ((const float4*)(xres + (size_t)row * 1024))[tid];
    float4 v;
    v.x = bf2f(a0[0]) + bf2f(a1[0]) + xr.x;
    v.y = bf2f(a0[1]) + bf2f(a1[1]) + xr.y;
    v.z = bf2f(a0[2]) + bf2f(a1[2]) + xr.z;
    v.w = bf2f(a0[3]) + bf2f(a1[3]) + xr.w;

    float s = v.x + v.y + v.z + v.w;
    float s2 = v.x * v.x + v.y * v.y + v.z * v.z + v.w * v.w;
#pragma unroll
    for (int d = 1; d < 64; d <<= 1) {
        s += __shfl_xor(s, d);
        s2 += __shfl_xor(s2, d);
    }
    __shared__ float red[8];
    const int wid = tid >> 6, lane = tid & 63;
    if (lane == 0) { red[wid] = s; red[4 + wid] = s2; }
    __syncthreads();
    s = red[0] + red[1] + red[2] + red[3];
    s2 = red[4] + red[5] + red[6] + red[7];
    const float mu = s * (1.f / 1024.f);
    const float var = s2 * (1.f / 1024.f) - mu * mu;
    const float rstd = rsqrtf(var + 1e-5f);
    const float4 gv = ((const float4*)gw)[tid];
    const float4 bv = ((const float4*)bw)[tid];
    float4 out;
    out.x = (v.x - mu) * rstd * gv.x + bv.x;
    out.y = (v.y - mu) * rstd * gv.y + bv.y;
    out.z = (v.z - mu) * rstd * gv.z + bv.z;
    out.w = (v.w - mu) * rstd * gv.w + bv.w;
    if (y) ((float4*)(y + (size_t)row * 1024))[tid] = out;
    if (ybf) {
        bf16* yb = ybf + base;
        yb[0] = bf16_rn(out.x);
        yb[1] = bf16_rn(out.y);
        yb[2] = bf16_rn(out.z);
        yb[3] = bf16_rn(out.w);
    }
}

// ---------------- fused fp32 -> bf16 for all 7 inputs (one launch) ----------------
// f4-cumulative segment bounds (src, inproj_w, outw, w1, w2, memk, memv):
//   1048576, 1835008, 2097152, 3145728, 4194304, 4202496, 4210688 (= 16448*256 exactly)
__global__ void cvt_all_kernel(const float* __restrict__ s0, const float* __restrict__ s1,
                               const float* __restrict__ s2, const float* __restrict__ s3,
                               const float* __restrict__ s4, const float* __restrict__ s5,
                               const float* __restrict__ s6, bf16* __restrict__ d0,
                               bf16* __restrict__ d1, bf16* __restrict__ d2, bf16* __restrict__ d3,
                               bf16* __restrict__ d4, bf16* __restrict__ d5, bf16* __restrict__ d6) {
    int i = blockIdx.x * 256 + threadIdx.x;
    const float* in;
    bf16* out;
    float scale = 1.f;
    if (i < 1048576) {
        in = s0; out = d0;
    } else if (i < 1835008) {
        in = s1; out = d1; i -= 1048576;
    } else if (i < 2097152) {
        in = s2; out = d2; i -= 1835008;
    } else if (i < 3145728) {
        in = s3; out = d3; i -= 2097152;
    } else if (i < 4194304) {
        in = s4; out = d4; i -= 3145728;
    } else if (i < 4202496) {
        in = s5; out = d5; i -= 4194304; scale = 8.f;  // memk * d^0.5 (log2e rides on q)
    } else {
        in = s6; out = d6; i -= 4202496; scale = 5.656854249492381f;  // memv * M^0.5
    }
    const float4 v = ((const float4*)in)[i];
    bf16* op = out + (size_t)i * 4;
    op[0] = bf16_rn(v.x * scale);
    op[1] = bf16_rn(v.y * scale);
    op[2] = bf16_rn(v.z * scale);
    op[3] = bf16_rn(v.w * scale);
}

extern "C" void kernel_launch(void* const* d_in, const int* in_sizes, int n_in, void* d_out,
                              int out_size, void* d_ws, size_t ws_size, hipStream_t stream) {
    const float* src = (const float*)d_in[0];
    const float* inproj_w = (const float*)d_in[1];
    const float* inproj_b = (const float*)d_in[2];
    const float* outw = (const float*)d_in[3];
    const float* outb = (const float*)d_in[4];
    const float* memk = (const float*)d_in[5];
    const float* memv = (const float*)d_in[6];
    const float* w1 = (const float*)d_in[7];
    const float* b1 = (const float*)d_in[8];
    const float* w2 = (const float*)d_in[9];
    const float* b2 = (const float*)d_in[10];
    const float* ln1g = (const float*)d_in[11];
    const float* ln1b = (const float*)d_in[12];
    const float* ln2g = (const float*)d_in[13];
    const float* ln2b = (const float*)d_in[14];

    char* ws = (char*)d_ws;
    const size_t MB = 1024 * 1024;
    bf16* w_inproj_bf = (bf16*)(ws + 0);          // 6 MB   [gemm1]
    bf16* w_out_bf = (bf16*)(ws + 6 * MB);        // 2 MB   [gemm2]
    bf16* w1_bf = (bf16*)(ws + 8 * MB);           // 8 MB   [gemm3]
    bf16* w2_bf = (bf16*)(ws + 16 * MB);          // 8 MB   [gemm4]
    bf16* mk_bf = (bf16*)(ws + 24 * MB);          // 64 KB  [attn]
    bf16* mv_bf = (bf16*)(ws + 24 * MB + 65536);  // 64 KB  [transpose_v]
    bf16* src_bf = (bf16*)(ws + 25 * MB);         // 8 MB   [gemm1]
    bf16* ctx_bf = src_bf;                        // reuse  [attn -> gemm2]
    bf16* qkv_bf = (bf16*)(ws + 33 * MB);         // 24 MB  [gemm1 -> attn]
    bf16* h_bf = qkv_bf;                          // 32 MB reuse [gemm3 -> gemm4]
    bf16* vt_bf = (bf16*)(ws + 65 * MB);          // 8.5 MB [transpose_v -> attn]
    bf16* g2p = vt_bf;                            // reuse  [split-K partials; vt dead by then]
    float* x_f = (float*)(ws + 81 * MB);          // 16 MB  [ln1 -> ln2 residual]
    bf16* x_bf = (bf16*)(ws + 97 * MB);           // 8 MB   [ln1 -> gemm3]
    float* outp = (float*)d_out;
    // split-K partials: base g2p (65..81 MB region, two contiguous 8MB slots).
    // gemm2 partials consumed by ln_sum1 before gemm4 reuses the same region.

    // one fused conversion launch (16448 * 256 threads == total f4 count exactly)
    cvt_all_kernel<<<dim3(16448), dim3(256), 0, stream>>>(
        src, inproj_w, outw, w1, w2, memk, memv,
        src_bf, w_inproj_bf, w_out_bf, w1_bf, w2_bf, mk_bf, mv_bf);

    // qkv = src @ in_proj_w^T + b  (q scaled by d^-0.5*log2e)
    gemm_bt<0><<<dim3(3072 / 128, 4096 / 128), 256, 0, stream>>>(
        src_bf, w_inproj_bf, inproj_b, qkv_bf, 4096, 3072, 1024, 1024);
    // VT = V^T (incl. mem tokens)
    transpose_v<<<dim3(33, 16, 2), 256, 0, stream>>>(qkv_bf, mv_bf, vt_bf);
    // ctx = softmax(q k^T) v    (grid: x=head for XCD L2 locality; 512 blocks)
    attn_kernel<<<dim3(16, 16, 2), 256, 0, stream>>>(qkv_bf, mk_bf, vt_bf, ctx_bf);
    // gemm2 split-K x2: partials = ctx @ out_w^T (+out_b on z=0), K=512 each
    gemm_bt<3><<<dim3(1024 / 128, 4096 / 128, 2), 256, 0, stream>>>(
        ctx_bf, w_out_bf, outb, g2p, 4096, 1024, 512, 1024);
    // x = LN1(p0 + p1 + src)
    ln_sum_kernel<<<dim3(4096), 256, 0, stream>>>(g2p, g2p + (size_t)4096 * 1024, src, ln1g, ln1b,
                                                  x_f, x_bf);
    // h = relu(x @ w1^T + b1)
    gemm_bt<2><<<dim3(4096 / 128, 4096 / 128), 256, 0, stream>>>(
        x_bf, w1_bf, b1, h_bf, 4096, 4096, 1024, 1024);
    // gemm4 split-K x2: partials = h @ w2^T (+b2 on z=0), K=2048 each
    gemm_bt<3><<<dim3(1024 / 128, 4096 / 128, 2), 256, 0, stream>>>(
        h_bf, w2_bf, b2, g2p, 4096, 1024, 2048, 4096);
    // out = LN2(p0 + p1 + x)
    ln_sum_kernel<<<dim3(4096), 256, 0, stream>>>(g2p, g2p + (size_t)4096 * 1024, x_f, ln2g, ln2b,
                                                  outp, nullptr);
}

// Round 13
// 233.124 us; speedup vs baseline: 1.0871x; 1.0133x over previous
//
#include <hip/hip_runtime.h>
#include <hip/hip_bf16.h>
#include <cstdint>

// Pipeline (all bf16 MFMA, fp32 accum):
//   cvt_all -> gemm1(qkv) -> transpose_v -> attn(flash, LDS-staged K/V, no-max exp2)
//   -> gemm2(split-K x4, bf16 partials) -> ln_sum1(+src) -> gemm3(relu)
//   -> gemm4(split-K x4, bf16 partials) -> ln_sum2(+x_bf)
// Round-13: split-K x2 -> x4 on gemm2/gemm4 (round-9 counters: latency-bound at
// low blocks/CU; x2 gave 84->~50us, x4 -> 4 blocks/CU). ln_sum reads 4 partials;
// ln2 residual now bf16 x_bf (drops x_f, keeps ws <= 97MB). Partials ping-pong
// between dead qkv region (gemm2) and dead vt region (gemm4).
// attn/gemm1/gemm3/cvt byte-identical to round 12 (proven under replay).

using bf16 = __hip_bfloat16;
typedef __attribute__((ext_vector_type(8))) __bf16 bf16x8;
typedef __attribute__((ext_vector_type(4))) __bf16 bf16x4;
typedef __attribute__((ext_vector_type(4))) float f32x4;

__device__ __forceinline__ void gload_lds16(const void* g, void* l) {
    auto gp = (const __attribute__((address_space(1))) void*)(uintptr_t)g;
    auto lp = (__attribute__((address_space(3))) void*)(uint32_t)(uintptr_t)l;
    __builtin_amdgcn_global_load_lds(gp, lp, 16, 0, 0);
}

// raw v_exp_f32 (1 instr) — scores are small/finite, no guard path needed
__device__ __forceinline__ float fast_exp2(float x) {
#if __has_builtin(__builtin_amdgcn_exp2f)
    return __builtin_amdgcn_exp2f(x);
#else
    float r;
    asm("v_exp_f32 %0, %1" : "=v"(r) : "v"(x));
    return r;
#endif
}

// 2-instr f32->bf16 (round-to-nearest). Inputs finite; bias far below threshold.
__device__ __forceinline__ bf16 bf16_rn(float x) {
    uint32_t u = __builtin_bit_cast(uint32_t, x);
    uint16_t h = (uint16_t)((u + 0x8000u) >> 16);
    return __builtin_bit_cast(bf16, h);
}

__device__ __forceinline__ float bf2f(__bf16 x) {
    return (float)x;
}

// ---------------- GEMM: C[M,N] = A[M,K] * B[N,K]^T (+bias, epilogue) ----------------
// EPI 0: qkv -> bf16, cols < 1024 scaled by d^-0.5 * log2(e)
// EPI 2: bf16 out = relu(acc + bias)
// EPI 3: split-K partial (gridDim.z=Z): slice z covers K columns [z*K, z*K+K) of
//        A/B (row stride lda), writes bf16 partial to Cb + z*M*N; z=0 adds bias.
template <int EPI>
__global__ __launch_bounds__(256, 2) void gemm_bt(
    const bf16* __restrict__ A, const bf16* __restrict__ B,
    const float* __restrict__ bias, bf16* __restrict__ Cb,
    int M, int N, int K, int lda) {
    __shared__ alignas(16) bf16 As[128 * 32];
    __shared__ alignas(16) bf16 Bs[128 * 32];

    const int tid = threadIdx.x;
    const int wid = tid >> 6;
    const int lane = tid & 63;
    const int g = lane >> 4;
    const int li = lane & 15;

    if (EPI == 3) {
        const int zo = blockIdx.z * K;
        A += zo;
        B += zo;
    }

    // XCD-aware bijective swizzle (all grids here have nwg % 8 == 0)
    int wg = blockIdx.y * gridDim.x + blockIdx.x;
    const int nwg = gridDim.x * gridDim.y;
    const int cpx = nwg >> 3;
    wg = (wg & 7) * cpx + (wg >> 3);
    const int bx = wg % (int)gridDim.x;
    const int by = wg / (int)gridDim.x;

    const int row0 = by * 128;
    const int col0 = bx * 128;
    const int wr = (wid >> 1) * 64;
    const int wc = (wid & 1) * 64;

    const int c0 = wid, c1 = wid + 4;
    const int srow = lane >> 2;
    const int scol = (lane & 3) * 8;

    const bf16* Ag0 = A + (size_t)(row0 + c0 * 16 + srow) * lda + scol;
    const bf16* Ag1 = A + (size_t)(row0 + c1 * 16 + srow) * lda + scol;
    const bf16* Bg0 = B + (size_t)(col0 + c0 * 16 + srow) * lda + scol;
    const bf16* Bg1 = B + (size_t)(col0 + c1 * 16 + srow) * lda + scol;

    bf16* lA0 = &As[c0 * 512];
    bf16* lA1 = &As[c1 * 512];
    bf16* lB0 = &Bs[c0 * 512];
    bf16* lB1 = &Bs[c1 * 512];

    f32x4 acc[4][4];
#pragma unroll
    for (int i = 0; i < 4; ++i)
#pragma unroll
        for (int j = 0; j < 4; ++j) acc[i][j] = (f32x4){0.f, 0.f, 0.f, 0.f};

    for (int k0 = 0; k0 < K; k0 += 32) {
        gload_lds16(Ag0 + k0, lA0);
        gload_lds16(Ag1 + k0, lA1);
        gload_lds16(Bg0 + k0, lB0);
        gload_lds16(Bg1 + k0, lB1);
        __syncthreads();

        bf16x8 af[4], bfr[4];
#pragma unroll
        for (int i = 0; i < 4; ++i) {
            af[i] = *(const bf16x8*)&As[(wr + i * 16 + li) * 32 + g * 8];
            bfr[i] = *(const bf16x8*)&Bs[(wc + i * 16 + li) * 32 + g * 8];
        }
#pragma unroll
        for (int i = 0; i < 4; ++i)
#pragma unroll
            for (int j = 0; j < 4; ++j)
                acc[i][j] = __builtin_amdgcn_mfma_f32_16x16x32_bf16(af[i], bfr[j], acc[i][j], 0, 0, 0);
        __syncthreads();
    }

#pragma unroll
    for (int i = 0; i < 4; ++i) {
#pragma unroll
        for (int j = 0; j < 4; ++j) {
            const int col = col0 + wc + j * 16 + li;
            const float bv = (EPI == 3 && blockIdx.z != 0) ? 0.f : bias[col];
#pragma unroll
            for (int r = 0; r < 4; ++r) {
                const int row = row0 + wr + i * 16 + g * 4 + r;
                const size_t idx = (size_t)row * N + col;
                float v = acc[i][j][r] + bv;
                if (EPI == 0) {
                    if (col < 1024) v *= 0.18033688011112042f;  // d^-0.5 * log2(e)
                    Cb[idx] = bf16_rn(v);
                } else if (EPI == 2) {
                    Cb[idx] = bf16_rn(v > 0.f ? v : 0.f);
                } else {  // EPI == 3
                    Cb[(size_t)blockIdx.z * ((size_t)M * N) + idx] = bf16_rn(v);
                }
            }
        }
    }
}

// ---------------- V transpose: VT[(b*16+h)*64 + d][s] for s in [0,2080) ----------------
__global__ __launch_bounds__(256) void transpose_v(const bf16* __restrict__ qkv,
                                                   const bf16* __restrict__ mv,
                                                   bf16* __restrict__ vt) {
    __shared__ bf16 tile[64][72];
    const int t = blockIdx.x;  // 0..32 (32 = mem-token tile, 32 rows)
    const int h = blockIdx.y;
    const int b = blockIdx.z;
    const int tid = threadIdx.x;
    const int r = tid >> 2;
    const int c = (tid & 3) * 16;
    const int s0 = t * 64;
    if (t < 32) {
        const bf16* p = qkv + (size_t)((s0 + r) * 2 + b) * 3072 + 2048 + h * 64 + c;
        *(bf16x8*)&tile[r][c] = *(const bf16x8*)p;
        *(bf16x8*)&tile[r][c + 8] = *(const bf16x8*)(p + 8);
    } else if (r < 32) {
        const bf16* p = mv + (size_t)r * 1024 + h * 64 + c;
        *(bf16x8*)&tile[r][c] = *(const bf16x8*)p;
        *(bf16x8*)&tile[r][c + 8] = *(const bf16x8*)(p + 8);
    }
    __syncthreads();
    const int d = tid >> 2;
    const int sc = (tid & 3) * 16;
    const int smax = (t < 32) ? 64 : 32;
    if (sc < smax) {
        bf16 tmp[16];
#pragma unroll
        for (int j = 0; j < 16; ++j) tmp[j] = tile[sc + j][d];
        bf16* q = vt + (size_t)((b * 16 + h) * 64 + d) * 2080 + s0 + sc;
        *(bf16x8*)q = *(const bf16x8*)&tmp[0];
        *(bf16x8*)(q + 8) = *(const bf16x8*)&tmp[8];
    }
}

// ---------------- flash attention (no-max exp2 softmax, LDS-staged K/V) ----------------
// Round-12 kernel verbatim (61.8 us proven): 4 waves x 32 q-rows, x=head grid,
// block-level double-buffered K/V staging, T5 setprio around MFMA clusters.
__global__ __launch_bounds__(256, 2) void attn_kernel(
    const bf16* __restrict__ qkv, const bf16* __restrict__ mk,
    const bf16* __restrict__ vt, bf16* __restrict__ ctx) {
    __shared__ alignas(16) bf16 Kst[2][64 * 64];
    __shared__ alignas(16) bf16 Vst[2][64 * 64];
    __shared__ alignas(16) bf16 Plds[4][32 * 64];

    const int tid = threadIdx.x;
    const int wid = tid >> 6;
    const int lane = tid & 63;
    const int g = lane >> 4;
    const int li = lane & 15;

    const int h = blockIdx.x;
    const int b = blockIdx.z;
    const int q0 = blockIdx.y * 128 + wid * 32;

    bf16* pl = &Plds[wid][0];
    const bf16* vth = vt + (size_t)((b * 16 + h) * 64) * 2080;

    const int srow8 = lane >> 3;           // row & 7
    const int sslot = (lane & 7) ^ srow8;  // swizzled 16B slot in the row

#define STAGE_KV(buf, t)                                                                       \
    {                                                                                          \
        const int _s0 = (t) * 64;                                                              \
        _Pragma("unroll") for (int j = 0; j < 2; ++j) {                                        \
            const int rw = (wid * 2 + j) * 8 + srow8;                                          \
            gload_lds16(qkv + (size_t)((_s0 + rw) * 2 + b) * 3072 + 1024 + h * 64 + sslot * 8, \
                        &Kst[buf][(wid * 2 + j) * 512]);                                       \
            gload_lds16(vth + (size_t)rw * 2080 + _s0 + sslot * 8,                             \
                        &Vst[buf][(wid * 2 + j) * 512]);                                       \
        }                                                                                      \
    }

    bf16x8 qf[2][2];
#pragma unroll
    for (int mi = 0; mi < 2; ++mi)
#pragma unroll
        for (int kd = 0; kd < 2; ++kd)
            qf[mi][kd] = *(const bf16x8*)(qkv + (size_t)((q0 + mi * 16 + li) * 2 + b) * 3072 +
                                          h * 64 + kd * 32 + g * 8);

    f32x4 o[2][4];
    float lrow[2][4];
#pragma unroll
    for (int mi = 0; mi < 2; ++mi) {
#pragma unroll
        for (int ni = 0; ni < 4; ++ni) o[mi][ni] = (f32x4){0.f, 0.f, 0.f, 0.f};
#pragma unroll
        for (int r = 0; r < 4; ++r) lrow[mi][r] = 0.f;
    }

    STAGE_KV(0, 0);

    for (int t = 0; t < 32; ++t) {
        const int cur = t & 1;
        __syncthreads();  // buf[cur] staged (compiler drains vmcnt) & prior readers done
        if (t < 31) STAGE_KV(cur ^ 1, t + 1);

        bf16x8 kf[4][2];
#pragma unroll
        for (int si = 0; si < 4; ++si)
#pragma unroll
            for (int kd = 0; kd < 2; ++kd)
                kf[si][kd] = *(const bf16x8*)&Kst[cur][(si * 16 + li) * 64 +
                                                       (((kd * 4 + g) ^ (li & 7)) * 8)];

        f32x4 sa[2][4];
#pragma unroll
        for (int mi = 0; mi < 2; ++mi)
#pragma unroll
            for (int si = 0; si < 4; ++si) sa[mi][si] = (f32x4){0.f, 0.f, 0.f, 0.f};
        __builtin_amdgcn_s_setprio(1);
#pragma unroll
        for (int mi = 0; mi < 2; ++mi)
#pragma unroll
            for (int si = 0; si < 4; ++si)
#pragma unroll
                for (int kd = 0; kd < 2; ++kd)
                    sa[mi][si] = __builtin_amdgcn_mfma_f32_16x16x32_bf16(qf[mi][kd], kf[si][kd],
                                                                         sa[mi][si], 0, 0, 0);
        __builtin_amdgcn_s_setprio(0);

        bf16x8 vf[2][4];
#pragma unroll
        for (int sblk = 0; sblk < 2; ++sblk)
#pragma unroll
            for (int ni = 0; ni < 4; ++ni)
                vf[sblk][ni] = *(const bf16x8*)&Vst[cur][(ni * 16 + li) * 64 +
                                                         (((sblk * 4 + g) ^ (li & 7)) * 8)];

#pragma unroll
        for (int mi = 0; mi < 2; ++mi)
#pragma unroll
            for (int r = 0; r < 4; ++r) {
                float ps = 0.f;
#pragma unroll
                for (int si = 0; si < 4; ++si) {
                    const float p = fast_exp2(sa[mi][si][r]);
                    sa[mi][si][r] = p;
                    ps += p;
                }
                lrow[mi][r] += ps;
            }

#pragma unroll
        for (int mi = 0; mi < 2; ++mi)
#pragma unroll
            for (int si = 0; si < 4; ++si)
#pragma unroll
                for (int r = 0; r < 4; ++r) {
                    const int row = mi * 16 + g * 4 + r;
                    const int col = (si * 16 + li) ^ (((row >> 2) & 3) << 4);
                    pl[row * 64 + col] = bf16_rn(sa[mi][si][r]);
                }

        asm volatile("s_waitcnt lgkmcnt(0)" ::: "memory");
        __builtin_amdgcn_sched_barrier(0);  // rule #18: pin ops after the wait

        bf16x8 pa[2][2];
#pragma unroll
        for (int mi = 0; mi < 2; ++mi)
#pragma unroll
            for (int sblk = 0; sblk < 2; ++sblk) {
                const int row = mi * 16 + li;
                const int e = (sblk * 32 + g * 8) ^ (((row >> 2) & 3) << 4);
                pa[mi][sblk] = *(const bf16x8*)&pl[row * 64 + e];
            }

        __builtin_amdgcn_s_setprio(1);
#pragma unroll
        for (int sblk = 0; sblk < 2; ++sblk)
#pragma unroll
            for (int ni = 0; ni < 4; ++ni)
#pragma unroll
                for (int mi = 0; mi < 2; ++mi)
                    o[mi][ni] = __builtin_amdgcn_mfma_f32_16x16x32_bf16(pa[mi][sblk], vf[sblk][ni],
                                                                        o[mi][ni], 0, 0, 0);
        __builtin_amdgcn_s_setprio(0);
    }

    // ---- tail: 32 memory tokens (global reads, no LDS staging) ----
    {
        bf16x8 kf[2][2];
#pragma unroll
        for (int si = 0; si < 2; ++si)
#pragma unroll
            for (int kd = 0; kd < 2; ++kd)
                kf[si][kd] = *(const bf16x8*)(mk + (size_t)(si * 16 + li) * 1024 + h * 64 +
                                              kd * 32 + g * 8);
        bf16x8 vf[4];
#pragma unroll
        for (int ni = 0; ni < 4; ++ni)
            vf[ni] = *(const bf16x8*)(vth + (size_t)(ni * 16 + li) * 2080 + 2048 + g * 8);

        f32x4 sa[2][2];
#pragma unroll
        for (int mi = 0; mi < 2; ++mi)
#pragma unroll
            for (int si = 0; si < 2; ++si) sa[mi][si] = (f32x4){0.f, 0.f, 0.f, 0.f};
#pragma unroll
        for (int mi = 0; mi < 2; ++mi)
#pragma unroll
            for (int si = 0; si < 2; ++si)
#pragma unroll
                for (int kd = 0; kd < 2; ++kd)
                    sa[mi][si] = __builtin_amdgcn_mfma_f32_16x16x32_bf16(qf[mi][kd], kf[si][kd],
                                                                         sa[mi][si], 0, 0, 0);
#pragma unroll
        for (int mi = 0; mi < 2; ++mi)
#pragma unroll
            for (int r = 0; r < 4; ++r) {
                float ps = 0.f;
#pragma unroll
                for (int si = 0; si < 2; ++si) {
                    const float p = fast_exp2(sa[mi][si][r]);
                    sa[mi][si][r] = p;
                    ps += p;
                }
                lrow[mi][r] += ps;
            }
#pragma unroll
        for (int mi = 0; mi < 2; ++mi)
#pragma unroll
            for (int si = 0; si < 2; ++si)
#pragma unroll
                for (int r = 0; r < 4; ++r) {
                    const int row = mi * 16 + g * 4 + r;
                    const int col = (si * 16 + li) ^ (((row >> 2) & 3) << 4);
                    pl[row * 64 + col] = bf16_rn(sa[mi][si][r]);
                }

        asm volatile("s_waitcnt lgkmcnt(0)" ::: "memory");
        __builtin_amdgcn_sched_barrier(0);

        bf16x8 pa[2];
#pragma unroll
        for (int mi = 0; mi < 2; ++mi) {
            const int row = mi * 16 + li;
            const int e = (g * 8) ^ (((row >> 2) & 3) << 4);
            pa[mi] = *(const bf16x8*)&pl[row * 64 + e];
        }
#pragma unroll
        for (int ni = 0; ni < 4; ++ni)
#pragma unroll
            for (int mi = 0; mi < 2; ++mi)
                o[mi][ni] = __builtin_amdgcn_mfma_f32_16x16x32_bf16(pa[mi], vf[ni], o[mi][ni], 0, 0, 0);
    }

    // epilogue: one shuffle-reduce of the deferred row sums, then scatter
#pragma unroll
    for (int mi = 0; mi < 2; ++mi)
#pragma unroll
        for (int r = 0; r < 4; ++r) {
            float s = lrow[mi][r];
#pragma unroll
            for (int d = 1; d < 16; d <<= 1) s += __shfl_xor(s, d);
            const float inv = 1.f / s;
            const int trow = q0 + mi * 16 + g * 4 + r;
#pragma unroll
            for (int ni = 0; ni < 4; ++ni)
                ctx[(size_t)(trow * 2 + b) * 1024 + h * 64 + ni * 16 + li] =
                    bf16_rn(o[mi][ni][r] * inv);
        }
#undef STAGE_KV
}

// ---------------- LayerNorm over rows of 1024: y = LN(p0+p1+p2+p3 + res) ----------------
// pbase: 4 bf16 split-K partials at stride 4096*1024 (p0 carries the bias).
// Residual: resf (fp32) or resb (bf16) — exactly one non-null.
__global__ __launch_bounds__(256, 4) void ln_sum_kernel(
    const bf16* __restrict__ pbase, const float* __restrict__ resf,
    const bf16* __restrict__ resb, const float* __restrict__ gw, const float* __restrict__ bw,
    float* __restrict__ y, bf16* __restrict__ ybf) {
    const int row = blockIdx.x;
    const int tid = threadIdx.x;
    const size_t base = (size_t)row * 1024 + tid * 4;
    const size_t PS = (size_t)4096 * 1024;

    float4 v = {0.f, 0.f, 0.f, 0.f};
#pragma unroll
    for (int z = 0; z < 4; ++z) {
        const bf16x4 a = *(const bf16x4*)(pbase + z * PS + base);
        v.x += bf2f(a[0]);
        v.y += bf2f(a[1]);
        v.z += bf2f(a[2]);
        v.w += bf2f(a[3]);
    }
    if (resf) {
        const float4 xr = ((const float4*)(resf + (size_t)row * 1024))[tid];
        v.x += xr.x; v.y += xr.y; v.z += xr.z; v.w += xr.w;
    } else {
        const bf16x4 xr = *(const bf16x4*)(resb + base);
        v.x += bf2f(xr[0]); v.y += bf2f(xr[1]); v.z += bf2f(xr[2]); v.w += bf2f(xr[3]);
    }

    float s = v.x + v.y + v.z + v.w;
    float s2 = v.x * v.x + v.y * v.y + v.z * v.z + v.w * v.w;
#pragma unroll
    for (int d = 1; d < 64; d <<= 1) {
        s += __shfl_xor(s, d);
        s2 += __shfl_xor(s2, d);
    }
    __shared__ float red[8];
    const int wid = tid >> 6, lane = tid & 63;
    if (lane == 0) { red[wid] = s; red[4 + wid] = s2; }
    __syncthreads();
    s = red[0] + red[1] + red[2] + red[3];
    s2 = red[4] + red[5] + red[6] + red[7];
    const float mu = s * (1.f / 1024.f);
    const float var = s2 * (1.f / 1024.f) - mu * mu;
    const float rstd = rsqrtf(var + 1e-5f);
    const float4 gv = ((const float4*)gw)[tid];
    const float4 bv = ((const float4*)bw)[tid];
    float4 out;
    out.x = (v.x - mu) * rstd * gv.x + bv.x;
    out.y = (v.y - mu) * rstd * gv.y + bv.y;
    out.z = (v.z - mu) * rstd * gv.z + bv.z;
    out.w = (v.w - mu) * rstd * gv.w + bv.w;
    if (y) ((float4*)(y + (size_t)row * 1024))[tid] = out;
    if (ybf) {
        bf16* yb = ybf + base;
        yb[0] = bf16_rn(out.x);
        yb[1] = bf16_rn(out.y);
        yb[2] = bf16_rn(out.z);
        yb[3] = bf16_rn(out.w);
    }
}

// ---------------- fused fp32 -> bf16 for all 7 inputs (one launch) ----------------
// f4-cumulative segment bounds (src, inproj_w, outw, w1, w2, memk, memv):
//   1048576, 1835008, 2097152, 3145728, 4194304, 4202496, 4210688 (= 16448*256 exactly)
__global__ void cvt_all_kernel(const float* __restrict__ s0, const float* __restrict__ s1,
                               const float* __restrict__ s2, const float* __restrict__ s3,
                               const float* __restrict__ s4, const float* __restrict__ s5,
                               const float* __restrict__ s6, bf16* __restrict__ d0,
                               bf16* __restrict__ d1, bf16* __restrict__ d2, bf16* __restrict__ d3,
                               bf16* __restrict__ d4, bf16* __restrict__ d5, bf16* __restrict__ d6) {
    int i = blockIdx.x * 256 + threadIdx.x;
    const float* in;
    bf16* out;
    float scale = 1.f;
    if (i < 1048576) {
        in = s0; out = d0;
    } else if (i < 1835008) {
        in = s1; out = d1; i -= 1048576;
    } else if (i < 2097152) {
        in = s2; out = d2; i -= 1835008;
    } else if (i < 3145728) {
        in = s3; out = d3; i -= 2097152;
    } else if (i < 4194304) {
        in = s4; out = d4; i -= 3145728;
    } else if (i < 4202496) {
        in = s5; out = d5; i -= 4194304; scale = 8.f;  // memk * d^0.5 (log2e rides on q)
    } else {
        in = s6; out = d6; i -= 4202496; scale = 5.656854249492381f;  // memv * M^0.5
    }
    const float4 v = ((const float4*)in)[i];
    bf16* op = out + (size_t)i * 4;
    op[0] = bf16_rn(v.x * scale);
    op[1] = bf16_rn(v.y * scale);
    op[2] = bf16_rn(v.z * scale);
    op[3] = bf16_rn(v.w * scale);
}

extern "C" void kernel_launch(void* const* d_in, const int* in_sizes, int n_in, void* d_out,
                              int out_size, void* d_ws, size_t ws_size, hipStream_t stream) {
    const float* src = (const float*)d_in[0];
    const float* inproj_w = (const float*)d_in[1];
    const float* inproj_b = (const float*)d_in[2];
    const float* outw = (const float*)d_in[3];
    const float* outb = (const float*)d_in[4];
    const float* memk = (const float*)d_in[5];
    const float* memv = (const float*)d_in[6];
    const float* w1 = (const float*)d_in[7];
    const float* b1 = (const float*)d_in[8];
    const float* w2 = (const float*)d_in[9];
    const float* b2 = (const float*)d_in[10];
    const float* ln1g = (const float*)d_in[11];
    const float* ln1b = (const float*)d_in[12];
    const float* ln2g = (const float*)d_in[13];
    const float* ln2b = (const float*)d_in[14];

    char* ws = (char*)d_ws;
    const size_t MB = 1024 * 1024;
    // Live-range plan (ws <= 97 MB):
    //   0..24   weights bf16 (inproj 6 | outw 2 | w1 8 | w2 8)
    //   24..25  mk_bf, mv_bf
    //   25..33  src_bf -> ctx (attn out) -> x_bf (ln1 out)
    //   33..57  qkv (gemm1 out) | 33..65 gemm2 partials (qkv dead) -> h (gemm3 out)
    //   65..97  vt (8.5MB, transpose_v -> attn) -> gemm4 partials (vt dead)
    bf16* w_inproj_bf = (bf16*)(ws + 0);
    bf16* w_out_bf = (bf16*)(ws + 6 * MB);
    bf16* w1_bf = (bf16*)(ws + 8 * MB);
    bf16* w2_bf = (bf16*)(ws + 16 * MB);
    bf16* mk_bf = (bf16*)(ws + 24 * MB);
    bf16* mv_bf = (bf16*)(ws + 24 * MB + 65536);
    bf16* src_bf = (bf16*)(ws + 25 * MB);
    bf16* ctx_bf = src_bf;     // attn out (src_bf dead after gemm1)
    bf16* x_bf = src_bf;       // ln1 out (ctx dead after gemm2)
    bf16* qkv_bf = (bf16*)(ws + 33 * MB);
    bf16* g2p = qkv_bf;        // gemm2 partials 4x8MB (qkv dead after attn)
    bf16* h_bf = qkv_bf;       // gemm3 out (partials dead after ln_sum1)
    bf16* vt_bf = (bf16*)(ws + 65 * MB);
    bf16* g4p = vt_bf;         // gemm4 partials 4x8MB (vt dead after attn)
    float* outp = (float*)d_out;

    // one fused conversion launch (16448 * 256 threads == total f4 count exactly)
    cvt_all_kernel<<<dim3(16448), dim3(256), 0, stream>>>(
        src, inproj_w, outw, w1, w2, memk, memv,
        src_bf, w_inproj_bf, w_out_bf, w1_bf, w2_bf, mk_bf, mv_bf);

    // qkv = src @ in_proj_w^T + b  (q scaled by d^-0.5*log2e)
    gemm_bt<0><<<dim3(3072 / 128, 4096 / 128), 256, 0, stream>>>(
        src_bf, w_inproj_bf, inproj_b, qkv_bf, 4096, 3072, 1024, 1024);
    // VT = V^T (incl. mem tokens)
    transpose_v<<<dim3(33, 16, 2), 256, 0, stream>>>(qkv_bf, mv_bf, vt_bf);
    // ctx = softmax(q k^T) v    (grid: x=head for XCD L2 locality; 512 blocks)
    attn_kernel<<<dim3(16, 16, 2), 256, 0, stream>>>(qkv_bf, mk_bf, vt_bf, ctx_bf);
    // gemm2 split-K x4: partials = ctx @ out_w^T (+out_b on z=0), K=256 each
    gemm_bt<3><<<dim3(1024 / 128, 4096 / 128, 4), 256, 0, stream>>>(
        ctx_bf, w_out_bf, outb, g2p, 4096, 1024, 256, 1024);
    // x = LN1(p0..p3 + src)  -> bf16 only
    ln_sum_kernel<<<dim3(4096), 256, 0, stream>>>(g2p, src, nullptr, ln1g, ln1b, nullptr, x_bf);
    // h = relu(x @ w1^T + b1)
    gemm_bt<2><<<dim3(4096 / 128, 4096 / 128), 256, 0, stream>>>(
        x_bf, w1_bf, b1, h_bf, 4096, 4096, 1024, 1024);
    // gemm4 split-K x4: partials = h @ w2^T (+b2 on z=0), K=1024 each
    gemm_bt<3><<<dim3(1024 / 128, 4096 / 128, 4), 256, 0, stream>>>(
        h_bf, w2_bf, b2, g4p, 4096, 1024, 1024, 4096);
    // out = LN2(p0..p3 + x)
    ln_sum_kernel<<<dim3(4096), 256, 0, stream>>>(g4p, nullptr, x_bf, ln2g, ln2b, outp, nullptr);
}

// Round 14
// 232.788 us; speedup vs baseline: 1.0886x; 1.0014x over previous
//
#include <hip/hip_runtime.h>
#include <hip/hip_bf16.h>
#include <cstdint>

// Pipeline (all bf16 MFMA, fp32 accum):
//   cvt_all -> gemm1(qkv) -> transpose_v -> attn(flash, LDS-staged K/V, no-max exp2)
//   -> gemm2(split-K x4, bf16 partials) -> ln_sum1(+src) -> gemm3(relu)
//   -> gemm4(split-K x4, bf16 partials) -> ln_sum2(+x_bf)
// Round-13: split-K x2 -> x4 on gemm2/gemm4 (round-9 counters: latency-bound at
// low blocks/CU; x2 gave 84->~50us, x4 -> 4 blocks/CU). ln_sum reads 4 partials;
// ln2 residual now bf16 x_bf (drops x_f, keeps ws <= 97MB). Partials ping-pong
// between dead qkv region (gemm2) and dead vt region (gemm4).
// attn/gemm1/gemm3/cvt byte-identical to round 12 (proven under replay).

using bf16 = __hip_bfloat16;
typedef __attribute__((ext_vector_type(8))) __bf16 bf16x8;
typedef __attribute__((ext_vector_type(4))) __bf16 bf16x4;
typedef __attribute__((ext_vector_type(4))) float f32x4;

__device__ __forceinline__ void gload_lds16(const void* g, void* l) {
    auto gp = (const __attribute__((address_space(1))) void*)(uintptr_t)g;
    auto lp = (__attribute__((address_space(3))) void*)(uint32_t)(uintptr_t)l;
    __builtin_amdgcn_global_load_lds(gp, lp, 16, 0, 0);
}

// raw v_exp_f32 (1 instr) — scores are small/finite, no guard path needed
__device__ __forceinline__ float fast_exp2(float x) {
#if __has_builtin(__builtin_amdgcn_exp2f)
    return __builtin_amdgcn_exp2f(x);
#else
    float r;
    asm("v_exp_f32 %0, %1" : "=v"(r) : "v"(x));
    return r;
#endif
}

// 2-instr f32->bf16 (round-to-nearest). Inputs finite; bias far below threshold.
__device__ __forceinline__ bf16 bf16_rn(float x) {
    uint32_t u = __builtin_bit_cast(uint32_t, x);
    uint16_t h = (uint16_t)((u + 0x8000u) >> 16);
    return __builtin_bit_cast(bf16, h);
}

__device__ __forceinline__ float bf2f(__bf16 x) {
    return (float)x;
}

// ---------------- GEMM: C[M,N] = A[M,K] * B[N,K]^T (+bias, epilogue) ----------------
// EPI 0: qkv -> bf16, cols < 1024 scaled by d^-0.5 * log2(e)
// EPI 2: bf16 out = relu(acc + bias)
// EPI 3: split-K partial (gridDim.z=Z): slice z covers K columns [z*K, z*K+K) of
//        A/B (row stride lda), writes bf16 partial to Cb + z*M*N; z=0 adds bias.
template <int EPI>
__global__ __launch_bounds__(256, 2) void gemm_bt(
    const bf16* __restrict__ A, const bf16* __restrict__ B,
    const float* __restrict__ bias, bf16* __restrict__ Cb,
    int M, int N, int K, int lda) {
    __shared__ alignas(16) bf16 As[128 * 32];
    __shared__ alignas(16) bf16 Bs[128 * 32];

    const int tid = threadIdx.x;
    const int wid = tid >> 6;
    const int lane = tid & 63;
    const int g = lane >> 4;
    const int li = lane & 15;

    if (EPI == 3) {
        const int zo = blockIdx.z * K;
        A += zo;
        B += zo;
    }

    // XCD-aware bijective swizzle (all grids here have nwg % 8 == 0)
    int wg = blockIdx.y * gridDim.x + blockIdx.x;
    const int nwg = gridDim.x * gridDim.y;
    const int cpx = nwg >> 3;
    wg = (wg & 7) * cpx + (wg >> 3);
    const int bx = wg % (int)gridDim.x;
    const int by = wg / (int)gridDim.x;

    const int row0 = by * 128;
    const int col0 = bx * 128;
    const int wr = (wid >> 1) * 64;
    const int wc = (wid & 1) * 64;

    const int c0 = wid, c1 = wid + 4;
    const int srow = lane >> 2;
    const int scol = (lane & 3) * 8;

    const bf16* Ag0 = A + (size_t)(row0 + c0 * 16 + srow) * lda + scol;
    const bf16* Ag1 = A + (size_t)(row0 + c1 * 16 + srow) * lda + scol;
    const bf16* Bg0 = B + (size_t)(col0 + c0 * 16 + srow) * lda + scol;
    const bf16* Bg1 = B + (size_t)(col0 + c1 * 16 + srow) * lda + scol;

    bf16* lA0 = &As[c0 * 512];
    bf16* lA1 = &As[c1 * 512];
    bf16* lB0 = &Bs[c0 * 512];
    bf16* lB1 = &Bs[c1 * 512];

    f32x4 acc[4][4];
#pragma unroll
    for (int i = 0; i < 4; ++i)
#pragma unroll
        for (int j = 0; j < 4; ++j) acc[i][j] = (f32x4){0.f, 0.f, 0.f, 0.f};

    for (int k0 = 0; k0 < K; k0 += 32) {
        gload_lds16(Ag0 + k0, lA0);
        gload_lds16(Ag1 + k0, lA1);
        gload_lds16(Bg0 + k0, lB0);
        gload_lds16(Bg1 + k0, lB1);
        __syncthreads();

        bf16x8 af[4], bfr[4];
#pragma unroll
        for (int i = 0; i < 4; ++i) {
            af[i] = *(const bf16x8*)&As[(wr + i * 16 + li) * 32 + g * 8];
            bfr[i] = *(const bf16x8*)&Bs[(wc + i * 16 + li) * 32 + g * 8];
        }
#pragma unroll
        for (int i = 0; i < 4; ++i)
#pragma unroll
            for (int j = 0; j < 4; ++j)
                acc[i][j] = __builtin_amdgcn_mfma_f32_16x16x32_bf16(af[i], bfr[j], acc[i][j], 0, 0, 0);
        __syncthreads();
    }

#pragma unroll
    for (int i = 0; i < 4; ++i) {
#pragma unroll
        for (int j = 0; j < 4; ++j) {
            const int col = col0 + wc + j * 16 + li;
            const float bv = (EPI == 3 && blockIdx.z != 0) ? 0.f : bias[col];
#pragma unroll
            for (int r = 0; r < 4; ++r) {
                const int row = row0 + wr + i * 16 + g * 4 + r;
                const size_t idx = (size_t)row * N + col;
                float v = acc[i][j][r] + bv;
                if (EPI == 0) {
                    if (col < 1024) v *= 0.18033688011112042f;  // d^-0.5 * log2(e)
                    Cb[idx] = bf16_rn(v);
                } else if (EPI == 2) {
                    Cb[idx] = bf16_rn(v > 0.f ? v : 0.f);
                } else {  // EPI == 3
                    Cb[(size_t)blockIdx.z * ((size_t)M * N) + idx] = bf16_rn(v);
                }
            }
        }
    }
}

// ---------------- V transpose: VT[(b*16+h)*64 + d][s] for s in [0,2080) ----------------
__global__ __launch_bounds__(256) void transpose_v(const bf16* __restrict__ qkv,
                                                   const bf16* __restrict__ mv,
                                                   bf16* __restrict__ vt) {
    __shared__ bf16 tile[64][72];
    const int t = blockIdx.x;  // 0..32 (32 = mem-token tile, 32 rows)
    const int h = blockIdx.y;
    const int b = blockIdx.z;
    const int tid = threadIdx.x;
    const int r = tid >> 2;
    const int c = (tid & 3) * 16;
    const int s0 = t * 64;
    if (t < 32) {
        const bf16* p = qkv + (size_t)((s0 + r) * 2 + b) * 3072 + 2048 + h * 64 + c;
        *(bf16x8*)&tile[r][c] = *(const bf16x8*)p;
        *(bf16x8*)&tile[r][c + 8] = *(const bf16x8*)(p + 8);
    } else if (r < 32) {
        const bf16* p = mv + (size_t)r * 1024 + h * 64 + c;
        *(bf16x8*)&tile[r][c] = *(const bf16x8*)p;
        *(bf16x8*)&tile[r][c + 8] = *(const bf16x8*)(p + 8);
    }
    __syncthreads();
    const int d = tid >> 2;
    const int sc = (tid & 3) * 16;
    const int smax = (t < 32) ? 64 : 32;
    if (sc < smax) {
        bf16 tmp[16];
#pragma unroll
        for (int j = 0; j < 16; ++j) tmp[j] = tile[sc + j][d];
        bf16* q = vt + (size_t)((b * 16 + h) * 64 + d) * 2080 + s0 + sc;
        *(bf16x8*)q = *(const bf16x8*)&tmp[0];
        *(bf16x8*)(q + 8) = *(const bf16x8*)&tmp[8];
    }
}

// ---------------- flash attention (no-max exp2 softmax, LDS-staged K/V) ----------------
// Round-12 kernel verbatim (61.8 us proven): 4 waves x 32 q-rows, x=head grid,
// block-level double-buffered K/V staging, T5 setprio around MFMA clusters.
__global__ __launch_bounds__(256, 2) void attn_kernel(
    const bf16* __restrict__ qkv, const bf16* __restrict__ mk,
    const bf16* __restrict__ vt, bf16* __restrict__ ctx) {
    __shared__ alignas(16) bf16 Kst[2][64 * 64];
    __shared__ alignas(16) bf16 Vst[2][64 * 64];
    __shared__ alignas(16) bf16 Plds[4][32 * 64];

    const int tid = threadIdx.x;
    const int wid = tid >> 6;
    const int lane = tid & 63;
    const int g = lane >> 4;
    const int li = lane & 15;

    const int h = blockIdx.x;
    const int b = blockIdx.z;
    const int q0 = blockIdx.y * 128 + wid * 32;

    bf16* pl = &Plds[wid][0];
    const bf16* vth = vt + (size_t)((b * 16 + h) * 64) * 2080;

    const int srow8 = lane >> 3;           // row & 7
    const int sslot = (lane & 7) ^ srow8;  // swizzled 16B slot in the row

#define STAGE_KV(buf, t)                                                                       \
    {                                                                                          \
        const int _s0 = (t) * 64;                                                              \
        _Pragma("unroll") for (int j = 0; j < 2; ++j) {                                        \
            const int rw = (wid * 2 + j) * 8 + srow8;                                          \
            gload_lds16(qkv + (size_t)((_s0 + rw) * 2 + b) * 3072 + 1024 + h * 64 + sslot * 8, \
                        &Kst[buf][(wid * 2 + j) * 512]);                                       \
            gload_lds16(vth + (size_t)rw * 2080 + _s0 + sslot * 8,                             \
                        &Vst[buf][(wid * 2 + j) * 512]);                                       \
        }                                                                                      \
    }

    bf16x8 qf[2][2];
#pragma unroll
    for (int mi = 0; mi < 2; ++mi)
#pragma unroll
        for (int kd = 0; kd < 2; ++kd)
            qf[mi][kd] = *(const bf16x8*)(qkv + (size_t)((q0 + mi * 16 + li) * 2 + b) * 3072 +
                                          h * 64 + kd * 32 + g * 8);

    f32x4 o[2][4];
    float lrow[2][4];
#pragma unroll
    for (int mi = 0; mi < 2; ++mi) {
#pragma unroll
        for (int ni = 0; ni < 4; ++ni) o[mi][ni] = (f32x4){0.f, 0.f, 0.f, 0.f};
#pragma unroll
        for (int r = 0; r < 4; ++r) lrow[mi][r] = 0.f;
    }

    STAGE_KV(0, 0);

    for (int t = 0; t < 32; ++t) {
        const int cur = t & 1;
        __syncthreads();  // buf[cur] staged (compiler drains vmcnt) & prior readers done
        if (t < 31) STAGE_KV(cur ^ 1, t + 1);

        bf16x8 kf[4][2];
#pragma unroll
        for (int si = 0; si < 4; ++si)
#pragma unroll
            for (int kd = 0; kd < 2; ++kd)
                kf[si][kd] = *(const bf16x8*)&Kst[cur][(si * 16 + li) * 64 +
                                                       (((kd * 4 + g) ^ (li & 7)) * 8)];

        f32x4 sa[2][4];
#pragma unroll
        for (int mi = 0; mi < 2; ++mi)
#pragma unroll
            for (int si = 0; si < 4; ++si) sa[mi][si] = (f32x4){0.f, 0.f, 0.f, 0.f};
        __builtin_amdgcn_s_setprio(1);
#pragma unroll
        for (int mi = 0; mi < 2; ++mi)
#pragma unroll
            for (int si = 0; si < 4; ++si)
#pragma unroll
                for (int kd = 0; kd < 2; ++kd)
                    sa[mi][si] = __builtin_amdgcn_mfma_f32_16x16x32_bf16(qf[mi][kd], kf[si][kd],
                                                                         sa[mi][si], 0, 0, 0);
        __builtin_amdgcn_s_setprio(0);

        bf16x8 vf[2][4];
#pragma unroll
        for (int sblk = 0; sblk < 2; ++sblk)
#pragma unroll
            for (int ni = 0; ni < 4; ++ni)
                vf[sblk][ni] = *(const bf16x8*)&Vst[cur][(ni * 16 + li) * 64 +
                                                         (((sblk * 4 + g) ^ (li & 7)) * 8)];

#pragma unroll
        for (int mi = 0; mi < 2; ++mi)
#pragma unroll
            for (int r = 0; r < 4; ++r) {
                float ps = 0.f;
#pragma unroll
                for (int si = 0; si < 4; ++si) {
                    const float p = fast_exp2(sa[mi][si][r]);
                    sa[mi][si][r] = p;
                    ps += p;
                }
                lrow[mi][r] += ps;
            }

#pragma unroll
        for (int mi = 0; mi < 2; ++mi)
#pragma unroll
            for (int si = 0; si < 4; ++si)
#pragma unroll
                for (int r = 0; r < 4; ++r) {
                    const int row = mi * 16 + g * 4 + r;
                    const int col = (si * 16 + li) ^ (((row >> 2) & 3) << 4);
                    pl[row * 64 + col] = bf16_rn(sa[mi][si][r]);
                }

        asm volatile("s_waitcnt lgkmcnt(0)" ::: "memory");
        __builtin_amdgcn_sched_barrier(0);  // rule #18: pin ops after the wait

        bf16x8 pa[2][2];
#pragma unroll
        for (int mi = 0; mi < 2; ++mi)
#pragma unroll
            for (int sblk = 0; sblk < 2; ++sblk) {
                const int row = mi * 16 + li;
                const int e = (sblk * 32 + g * 8) ^ (((row >> 2) & 3) << 4);
                pa[mi][sblk] = *(const bf16x8*)&pl[row * 64 + e];
            }

        __builtin_amdgcn_s_setprio(1);
#pragma unroll
        for (int sblk = 0; sblk < 2; ++sblk)
#pragma unroll
            for (int ni = 0; ni < 4; ++ni)
#pragma unroll
                for (int mi = 0; mi < 2; ++mi)
                    o[mi][ni] = __builtin_amdgcn_mfma_f32_16x16x32_bf16(pa[mi][sblk], vf[sblk][ni],
                                                                        o[mi][ni], 0, 0, 0);
        __builtin_amdgcn_s_setprio(0);
    }

    // ---- tail: 32 memory tokens (global reads, no LDS staging) ----
    {
        bf16x8 kf[2][2];
#pragma unroll
        for (int si = 0; si < 2; ++si)
#pragma unroll
            for (int kd = 0; kd < 2; ++kd)
                kf[si][kd] = *(const bf16x8*)(mk + (size_t)(si * 16 + li) * 1024 + h * 64 +
                                              kd * 32 + g * 8);
        bf16x8 vf[4];
#pragma unroll
        for (int ni = 0; ni < 4; ++ni)
            vf[ni] = *(const bf16x8*)(vth + (size_t)(ni * 16 + li) * 2080 + 2048 + g * 8);

        f32x4 sa[2][2];
#pragma unroll
        for (int mi = 0; mi < 2; ++mi)
#pragma unroll
            for (int si = 0; si < 2; ++si) sa[mi][si] = (f32x4){0.f, 0.f, 0.f, 0.f};
#pragma unroll
        for (int mi = 0; mi < 2; ++mi)
#pragma unroll
            for (int si = 0; si < 2; ++si)
#pragma unroll
                for (int kd = 0; kd < 2; ++kd)
                    sa[mi][si] = __builtin_amdgcn_mfma_f32_16x16x32_bf16(qf[mi][kd], kf[si][kd],
                                                                         sa[mi][si], 0, 0, 0);
#pragma unroll
        for (int mi = 0; mi < 2; ++mi)
#pragma unroll
            for (int r = 0; r < 4; ++r) {
                float ps = 0.f;
#pragma unroll
                for (int si = 0; si < 2; ++si) {
                    const float p = fast_exp2(sa[mi][si][r]);
                    sa[mi][si][r] = p;
                    ps += p;
                }
                lrow[mi][r] += ps;
            }
#pragma unroll
        for (int mi = 0; mi < 2; ++mi)
#pragma unroll
            for (int si = 0; si < 2; ++si)
#pragma unroll
                for (int r = 0; r < 4; ++r) {
                    const int row = mi * 16 + g * 4 + r;
                    const int col = (si * 16 + li) ^ (((row >> 2) & 3) << 4);
                    pl[row * 64 + col] = bf16_rn(sa[mi][si][r]);
                }

        asm volatile("s_waitcnt lgkmcnt(0)" ::: "memory");
        __builtin_amdgcn_sched_barrier(0);

        bf16x8 pa[2];
#pragma unroll
        for (int mi = 0; mi < 2; ++mi) {
            const int row = mi * 16 + li;
            const int e = (g * 8) ^ (((row >> 2) & 3) << 4);
            pa[mi] = *(const bf16x8*)&pl[row * 64 + e];
        }
#pragma unroll
        for (int ni = 0; ni < 4; ++ni)
#pragma unroll
            for (int mi = 0; mi < 2; ++mi)
                o[mi][ni] = __builtin_amdgcn_mfma_f32_16x16x32_bf16(pa[mi], vf[ni], o[mi][ni], 0, 0, 0);
    }

    // epilogue: one shuffle-reduce of the deferred row sums, then scatter
#pragma unroll
    for (int mi = 0; mi < 2; ++mi)
#pragma unroll
        for (int r = 0; r < 4; ++r) {
            float s = lrow[mi][r];
#pragma unroll
            for (int d = 1; d < 16; d <<= 1) s += __shfl_xor(s, d);
            const float inv = 1.f / s;
            const int trow = q0 + mi * 16 + g * 4 + r;
#pragma unroll
            for (int ni = 0; ni < 4; ++ni)
                ctx[(size_t)(trow * 2 + b) * 1024 + h * 64 + ni * 16 + li] =
                    bf16_rn(o[mi][ni][r] * inv);
        }
#undef STAGE_KV
}

// ---------------- LayerNorm over rows of 1024: y = LN(p0+p1+p2+p3 + res) ----------------
// pbase: 4 bf16 split-K partials at stride 4096*1024 (p0 carries the bias).
// Residual: resf (fp32) or resb (bf16) — exactly one non-null.
__global__ __launch_bounds__(256, 4) void ln_sum_kernel(
    const bf16* __restrict__ pbase, const float* __restrict__ resf,
    const bf16* __restrict__ resb, const float* __restrict__ gw, const float* __restrict__ bw,
    float* __restrict__ y, bf16* __restrict__ ybf) {
    const int row = blockIdx.x;
    const int tid = threadIdx.x;
    const size_t base = (size_t)row * 1024 + tid * 4;
    const size_t PS = (size_t)4096 * 1024;

    float4 v = {0.f, 0.f, 0.f, 0.f};
#pragma unroll
    for (int z = 0; z < 4; ++z) {
        const bf16x4 a = *(const bf16x4*)(pbase + z * PS + base);
        v.x += bf2f(a[0]);
        v.y += bf2f(a[1]);
        v.z += bf2f(a[2]);
        v.w += bf2f(a[3]);
    }
    if (resf) {
        const float4 xr = ((const float4*)(resf + (size_t)row * 1024))[tid];
        v.x += xr.x; v.y += xr.y; v.z += xr.z; v.w += xr.w;
    } else {
        const bf16x4 xr = *(const bf16x4*)(resb + base);
        v.x += bf2f(xr[0]); v.y += bf2f(xr[1]); v.z += bf2f(xr[2]); v.w += bf2f(xr[3]);
    }

    float s = v.x + v.y + v.z + v.w;
    float s2 = v.x * v.x + v.y * v.y + v.z * v.z + v.w * v.w;
#pragma unroll
    for (int d = 1; d < 64; d <<= 1) {
        s += __shfl_xor(s, d);
        s2 += __shfl_xor(s2, d);
    }
    __shared__ float red[8];
    const int wid = tid >> 6, lane = tid & 63;
    if (lane == 0) { red[wid] = s; red[4 + wid] = s2; }
    __syncthreads();
    s = red[0] + red[1] + red[2] + red[3];
    s2 = red[4] + red[5] + red[6] + red[7];
    const float mu = s * (1.f / 1024.f);
    const float var = s2 * (1.f / 1024.f) - mu * mu;
    const float rstd = rsqrtf(var + 1e-5f);
    const float4 gv = ((const float4*)gw)[tid];
    const float4 bv = ((const float4*)bw)[tid];
    float4 out;
    out.x = (v.x - mu) * rstd * gv.x + bv.x;
    out.y = (v.y - mu) * rstd * gv.y + bv.y;
    out.z = (v.z - mu) * rstd * gv.z + bv.z;
    out.w = (v.w - mu) * rstd * gv.w + bv.w;
    if (y) ((float4*)(y + (size_t)row * 1024))[tid] = out;
    if (ybf) {
        bf16* yb = ybf + base;
        yb[0] = bf16_rn(out.x);
        yb[1] = bf16_rn(out.y);
        yb[2] = bf16_rn(out.z);
        yb[3] = bf16_rn(out.w);
    }
}

// ---------------- fused fp32 -> bf16 for all 7 inputs (one launch) ----------------
// f4-cumulative segment bounds (src, inproj_w, outw, w1, w2, memk, memv):
//   1048576, 1835008, 2097152, 3145728, 4194304, 4202496, 4210688 (= 16448*256 exactly)
__global__ void cvt_all_kernel(const float* __restrict__ s0, const float* __restrict__ s1,
                               const float* __restrict__ s2, const float* __restrict__ s3,
                               const float* __restrict__ s4, const float* __restrict__ s5,
                               const float* __restrict__ s6, bf16* __restrict__ d0,
                               bf16* __restrict__ d1, bf16* __restrict__ d2, bf16* __restrict__ d3,
                               bf16* __restrict__ d4, bf16* __restrict__ d5, bf16* __restrict__ d6) {
    int i = blockIdx.x * 256 + threadIdx.x;
    const float* in;
    bf16* out;
    float scale = 1.f;
    if (i < 1048576) {
        in = s0; out = d0;
    } else if (i < 1835008) {
        in = s1; out = d1; i -= 1048576;
    } else if (i < 2097152) {
        in = s2; out = d2; i -= 1835008;
    } else if (i < 3145728) {
        in = s3; out = d3; i -= 2097152;
    } else if (i < 4194304) {
        in = s4; out = d4; i -= 3145728;
    } else if (i < 4202496) {
        in = s5; out = d5; i -= 4194304; scale = 8.f;  // memk * d^0.5 (log2e rides on q)
    } else {
        in = s6; out = d6; i -= 4202496; scale = 5.656854249492381f;  // memv * M^0.5
    }
    const float4 v = ((const float4*)in)[i];
    bf16* op = out + (size_t)i * 4;
    op[0] = bf16_rn(v.x * scale);
    op[1] = bf16_rn(v.y * scale);
    op[2] = bf16_rn(v.z * scale);
    op[3] = bf16_rn(v.w * scale);
}

extern "C" void kernel_launch(void* const* d_in, const int* in_sizes, int n_in, void* d_out,
                              int out_size, void* d_ws, size_t ws_size, hipStream_t stream) {
    const float* src = (const float*)d_in[0];
    const float* inproj_w = (const float*)d_in[1];
    const float* inproj_b = (const float*)d_in[2];
    const float* outw = (const float*)d_in[3];
    const float* outb = (const float*)d_in[4];
    const float* memk = (const float*)d_in[5];
    const float* memv = (const float*)d_in[6];
    const float* w1 = (const float*)d_in[7];
    const float* b1 = (const float*)d_in[8];
    const float* w2 = (const float*)d_in[9];
    const float* b2 = (const float*)d_in[10];
    const float* ln1g = (const float*)d_in[11];
    const float* ln1b = (const float*)d_in[12];
    const float* ln2g = (const float*)d_in[13];
    const float* ln2b = (const float*)d_in[14];

    char* ws = (char*)d_ws;
    const size_t MB = 1024 * 1024;
    // Live-range plan (ws <= 97 MB):
    //   0..24   weights bf16 (inproj 6 | outw 2 | w1 8 | w2 8)
    //   24..25  mk_bf, mv_bf
    //   25..33  src_bf -> ctx (attn out) -> x_bf (ln1 out)
    //   33..57  qkv (gemm1 out) | 33..65 gemm2 partials (qkv dead) -> h (gemm3 out)
    //   65..97  vt (8.5MB, transpose_v -> attn) -> gemm4 partials (vt dead)
    bf16* w_inproj_bf = (bf16*)(ws + 0);
    bf16* w_out_bf = (bf16*)(ws + 6 * MB);
    bf16* w1_bf = (bf16*)(ws + 8 * MB);
    bf16* w2_bf = (bf16*)(ws + 16 * MB);
    bf16* mk_bf = (bf16*)(ws + 24 * MB);
    bf16* mv_bf = (bf16*)(ws + 24 * MB + 65536);
    bf16* src_bf = (bf16*)(ws + 25 * MB);
    bf16* ctx_bf = src_bf;     // attn out (src_bf dead after gemm1)
    bf16* x_bf = src_bf;       // ln1 out (ctx dead after gemm2)
    bf16* qkv_bf = (bf16*)(ws + 33 * MB);
    bf16* g2p = qkv_bf;        // gemm2 partials 4x8MB (qkv dead after attn)
    bf16* h_bf = qkv_bf;       // gemm3 out (partials dead after ln_sum1)
    bf16* vt_bf = (bf16*)(ws + 65 * MB);
    bf16* g4p = vt_bf;         // gemm4 partials 4x8MB (vt dead after attn)
    float* outp = (float*)d_out;

    // one fused conversion launch (16448 * 256 threads == total f4 count exactly)
    cvt_all_kernel<<<dim3(16448), dim3(256), 0, stream>>>(
        src, inproj_w, outw, w1, w2, memk, memv,
        src_bf, w_inproj_bf, w_out_bf, w1_bf, w2_bf, mk_bf, mv_bf);

    // qkv = src @ in_proj_w^T + b  (q scaled by d^-0.5*log2e)
    gemm_bt<0><<<dim3(3072 / 128, 4096 / 128), 256, 0, stream>>>(
        src_bf, w_inproj_bf, inproj_b, qkv_bf, 4096, 3072, 1024, 1024);
    // VT = V^T (incl. mem tokens)
    transpose_v<<<dim3(33, 16, 2), 256, 0, stream>>>(qkv_bf, mv_bf, vt_bf);
    // ctx = softmax(q k^T) v    (grid: x=head for XCD L2 locality; 512 blocks)
    attn_kernel<<<dim3(16, 16, 2), 256, 0, stream>>>(qkv_bf, mk_bf, vt_bf, ctx_bf);
    // gemm2 split-K x4: partials = ctx @ out_w^T (+out_b on z=0), K=256 each
    gemm_bt<3><<<dim3(1024 / 128, 4096 / 128, 4), 256, 0, stream>>>(
        ctx_bf, w_out_bf, outb, g2p, 4096, 1024, 256, 1024);
    // x = LN1(p0..p3 + src)  -> bf16 only
    ln_sum_kernel<<<dim3(4096), 256, 0, stream>>>(g2p, src, nullptr, ln1g, ln1b, nullptr, x_bf);
    // h = relu(x @ w1^T + b1)
    gemm_bt<2><<<dim3(4096 / 128, 4096 / 128), 256, 0, stream>>>(
        x_bf, w1_bf, b1, h_bf, 4096, 4096, 1024, 1024);
    // gemm4 split-K x4: partials = h @ w2^T (+b2 on z=0), K=1024 each
    gemm_bt<3><<<dim3(1024 / 128, 4096 / 128, 4), 256, 0, stream>>>(
        h_bf, w2_bf, b2, g4p, 4096, 1024, 1024, 4096);
    // out = LN2(p0..p3 + x)
    ln_sum_kernel<<<dim3(4096), 256, 0, stream>>>(g4p, nullptr, x_bf, ln2g, ln2b, outp, nullptr);
}

// Round 15
// 231.848 us; speedup vs baseline: 1.0930x; 1.0041x over previous
//
#include <hip/hip_runtime.h>
#include <hip/hip_bf16.h>
#include <cstdint>

// Pipeline (all bf16 MFMA, fp32 accum):
//   cvt_all -> gemm1(qkv) -> transpose_v -> attn(flash, 4-deep K/V ring, paired tiles)
//   -> gemm2(split-K x4, bf16 partials) -> ln_sum1(+src) -> gemm3(relu)
//   -> gemm4(split-K x4, bf16 partials) -> ln_sum2(+x_bf)
// Round-15: attn barriers halved — K/V ring buffer x4 (80KB LDS, still 2 blocks/CU),
// __syncthreads on even tiles only, staging 2 tiles ahead. Tile t+1's K-reads/QK^T/
// softmax overlap tile t's PV MFMAs in the barrier-free window. P-LDS reuse across
// the pair is safe: per-wave DS ops are in-order and compiler preserves alias order.
// GEMMs/LN/cvt byte-identical to round 14 (proven under replay).

using bf16 = __hip_bfloat16;
typedef __attribute__((ext_vector_type(8))) __bf16 bf16x8;
typedef __attribute__((ext_vector_type(4))) __bf16 bf16x4;
typedef __attribute__((ext_vector_type(4))) float f32x4;

__device__ __forceinline__ void gload_lds16(const void* g, void* l) {
    auto gp = (const __attribute__((address_space(1))) void*)(uintptr_t)g;
    auto lp = (__attribute__((address_space(3))) void*)(uint32_t)(uintptr_t)l;
    __builtin_amdgcn_global_load_lds(gp, lp, 16, 0, 0);
}

// raw v_exp_f32 (1 instr) — scores are small/finite, no guard path needed
__device__ __forceinline__ float fast_exp2(float x) {
#if __has_builtin(__builtin_amdgcn_exp2f)
    return __builtin_amdgcn_exp2f(x);
#else
    float r;
    asm("v_exp_f32 %0, %1" : "=v"(r) : "v"(x));
    return r;
#endif
}

// 2-instr f32->bf16 (round-to-nearest). Inputs finite; bias far below threshold.
__device__ __forceinline__ bf16 bf16_rn(float x) {
    uint32_t u = __builtin_bit_cast(uint32_t, x);
    uint16_t h = (uint16_t)((u + 0x8000u) >> 16);
    return __builtin_bit_cast(bf16, h);
}

__device__ __forceinline__ float bf2f(__bf16 x) {
    return (float)x;
}

// ---------------- GEMM: C[M,N] = A[M,K] * B[N,K]^T (+bias, epilogue) ----------------
// EPI 0: qkv -> bf16, cols < 1024 scaled by d^-0.5 * log2(e)
// EPI 2: bf16 out = relu(acc + bias)
// EPI 3: split-K partial (gridDim.z=Z): slice z covers K columns [z*K, z*K+K) of
//        A/B (row stride lda), writes bf16 partial to Cb + z*M*N; z=0 adds bias.
template <int EPI>
__global__ __launch_bounds__(256, 2) void gemm_bt(
    const bf16* __restrict__ A, const bf16* __restrict__ B,
    const float* __restrict__ bias, bf16* __restrict__ Cb,
    int M, int N, int K, int lda) {
    __shared__ alignas(16) bf16 As[128 * 32];
    __shared__ alignas(16) bf16 Bs[128 * 32];

    const int tid = threadIdx.x;
    const int wid = tid >> 6;
    const int lane = tid & 63;
    const int g = lane >> 4;
    const int li = lane & 15;

    if (EPI == 3) {
        const int zo = blockIdx.z * K;
        A += zo;
        B += zo;
    }

    // XCD-aware bijective swizzle (all grids here have nwg % 8 == 0)
    int wg = blockIdx.y * gridDim.x + blockIdx.x;
    const int nwg = gridDim.x * gridDim.y;
    const int cpx = nwg >> 3;
    wg = (wg & 7) * cpx + (wg >> 3);
    const int bx = wg % (int)gridDim.x;
    const int by = wg / (int)gridDim.x;

    const int row0 = by * 128;
    const int col0 = bx * 128;
    const int wr = (wid >> 1) * 64;
    const int wc = (wid & 1) * 64;

    const int c0 = wid, c1 = wid + 4;
    const int srow = lane >> 2;
    const int scol = (lane & 3) * 8;

    const bf16* Ag0 = A + (size_t)(row0 + c0 * 16 + srow) * lda + scol;
    const bf16* Ag1 = A + (size_t)(row0 + c1 * 16 + srow) * lda + scol;
    const bf16* Bg0 = B + (size_t)(col0 + c0 * 16 + srow) * lda + scol;
    const bf16* Bg1 = B + (size_t)(col0 + c1 * 16 + srow) * lda + scol;

    bf16* lA0 = &As[c0 * 512];
    bf16* lA1 = &As[c1 * 512];
    bf16* lB0 = &Bs[c0 * 512];
    bf16* lB1 = &Bs[c1 * 512];

    f32x4 acc[4][4];
#pragma unroll
    for (int i = 0; i < 4; ++i)
#pragma unroll
        for (int j = 0; j < 4; ++j) acc[i][j] = (f32x4){0.f, 0.f, 0.f, 0.f};

    for (int k0 = 0; k0 < K; k0 += 32) {
        gload_lds16(Ag0 + k0, lA0);
        gload_lds16(Ag1 + k0, lA1);
        gload_lds16(Bg0 + k0, lB0);
        gload_lds16(Bg1 + k0, lB1);
        __syncthreads();

        bf16x8 af[4], bfr[4];
#pragma unroll
        for (int i = 0; i < 4; ++i) {
            af[i] = *(const bf16x8*)&As[(wr + i * 16 + li) * 32 + g * 8];
            bfr[i] = *(const bf16x8*)&Bs[(wc + i * 16 + li) * 32 + g * 8];
        }
#pragma unroll
        for (int i = 0; i < 4; ++i)
#pragma unroll
            for (int j = 0; j < 4; ++j)
                acc[i][j] = __builtin_amdgcn_mfma_f32_16x16x32_bf16(af[i], bfr[j], acc[i][j], 0, 0, 0);
        __syncthreads();
    }

#pragma unroll
    for (int i = 0; i < 4; ++i) {
#pragma unroll
        for (int j = 0; j < 4; ++j) {
            const int col = col0 + wc + j * 16 + li;
            const float bv = (EPI == 3 && blockIdx.z != 0) ? 0.f : bias[col];
#pragma unroll
            for (int r = 0; r < 4; ++r) {
                const int row = row0 + wr + i * 16 + g * 4 + r;
                const size_t idx = (size_t)row * N + col;
                float v = acc[i][j][r] + bv;
                if (EPI == 0) {
                    if (col < 1024) v *= 0.18033688011112042f;  // d^-0.5 * log2(e)
                    Cb[idx] = bf16_rn(v);
                } else if (EPI == 2) {
                    Cb[idx] = bf16_rn(v > 0.f ? v : 0.f);
                } else {  // EPI == 3
                    Cb[(size_t)blockIdx.z * ((size_t)M * N) + idx] = bf16_rn(v);
                }
            }
        }
    }
}

// ---------------- V transpose: VT[(b*16+h)*64 + d][s] for s in [0,2080) ----------------
__global__ __launch_bounds__(256) void transpose_v(const bf16* __restrict__ qkv,
                                                   const bf16* __restrict__ mv,
                                                   bf16* __restrict__ vt) {
    __shared__ bf16 tile[64][72];
    const int t = blockIdx.x;  // 0..32 (32 = mem-token tile, 32 rows)
    const int h = blockIdx.y;
    const int b = blockIdx.z;
    const int tid = threadIdx.x;
    const int r = tid >> 2;
    const int c = (tid & 3) * 16;
    const int s0 = t * 64;
    if (t < 32) {
        const bf16* p = qkv + (size_t)((s0 + r) * 2 + b) * 3072 + 2048 + h * 64 + c;
        *(bf16x8*)&tile[r][c] = *(const bf16x8*)p;
        *(bf16x8*)&tile[r][c + 8] = *(const bf16x8*)(p + 8);
    } else if (r < 32) {
        const bf16* p = mv + (size_t)r * 1024 + h * 64 + c;
        *(bf16x8*)&tile[r][c] = *(const bf16x8*)p;
        *(bf16x8*)&tile[r][c + 8] = *(const bf16x8*)(p + 8);
    }
    __syncthreads();
    const int d = tid >> 2;
    const int sc = (tid & 3) * 16;
    const int smax = (t < 32) ? 64 : 32;
    if (sc < smax) {
        bf16 tmp[16];
#pragma unroll
        for (int j = 0; j < 16; ++j) tmp[j] = tile[sc + j][d];
        bf16* q = vt + (size_t)((b * 16 + h) * 64 + d) * 2080 + s0 + sc;
        *(bf16x8*)q = *(const bf16x8*)&tmp[0];
        *(bf16x8*)(q + 8) = *(const bf16x8*)&tmp[8];
    }
}

// ---------------- flash attention (no-max exp2 softmax, 4-deep K/V ring) ----------------
// Block = 4 waves x 32 q-rows. Grid (h, qtile, b): x=16 % 8 == 0 -> all blocks of
// head h share XCD h%8, K/V L2-resident. K/V staged once per block into a 4-slot
// ring; __syncthreads on even tiles only (16 barriers); stage runs 2 tiles ahead.
// Tile t+1's K-reads/QK^T overlap tile t's PV in the barrier-free window.
__global__ __launch_bounds__(256, 2) void attn_kernel(
    const bf16* __restrict__ qkv, const bf16* __restrict__ mk,
    const bf16* __restrict__ vt, bf16* __restrict__ ctx) {
    __shared__ alignas(16) bf16 Kst[4][64 * 64];
    __shared__ alignas(16) bf16 Vst[4][64 * 64];
    __shared__ alignas(16) bf16 Plds[4][32 * 64];

    const int tid = threadIdx.x;
    const int wid = tid >> 6;
    const int lane = tid & 63;
    const int g = lane >> 4;
    const int li = lane & 15;

    const int h = blockIdx.x;
    const int b = blockIdx.z;
    const int q0 = blockIdx.y * 128 + wid * 32;

    bf16* pl = &Plds[wid][0];
    const bf16* vth = vt + (size_t)((b * 16 + h) * 64) * 2080;

    const int srow8 = lane >> 3;           // row & 7
    const int sslot = (lane & 7) ^ srow8;  // swizzled 16B slot in the row

#define STAGE_KV(buf, t)                                                                       \
    {                                                                                          \
        const int _s0 = (t) * 64;                                                              \
        _Pragma("unroll") for (int j = 0; j < 2; ++j) {                                        \
            const int rw = (wid * 2 + j) * 8 + srow8;                                          \
            gload_lds16(qkv + (size_t)((_s0 + rw) * 2 + b) * 3072 + 1024 + h * 64 + sslot * 8, \
                        &Kst[buf][(wid * 2 + j) * 512]);                                       \
            gload_lds16(vth + (size_t)rw * 2080 + _s0 + sslot * 8,                             \
                        &Vst[buf][(wid * 2 + j) * 512]);                                       \
        }                                                                                      \
    }

    bf16x8 qf[2][2];
#pragma unroll
    for (int mi = 0; mi < 2; ++mi)
#pragma unroll
        for (int kd = 0; kd < 2; ++kd)
            qf[mi][kd] = *(const bf16x8*)(qkv + (size_t)((q0 + mi * 16 + li) * 2 + b) * 3072 +
                                          h * 64 + kd * 32 + g * 8);

    f32x4 o[2][4];
    float lrow[2][4];
#pragma unroll
    for (int mi = 0; mi < 2; ++mi) {
#pragma unroll
        for (int ni = 0; ni < 4; ++ni) o[mi][ni] = (f32x4){0.f, 0.f, 0.f, 0.f};
#pragma unroll
        for (int r = 0; r < 4; ++r) lrow[mi][r] = 0.f;
    }

    STAGE_KV(0, 0);
    STAGE_KV(1, 1);

    for (int tp = 0; tp < 16; ++tp) {
        const int t0 = tp * 2;
        __syncthreads();  // ring slots t0&3,(t0+1)&3 staged; prior readers of t0+2,t0+3 done
        if (t0 + 2 < 32) STAGE_KV((t0 + 2) & 3, t0 + 2);
        if (t0 + 3 < 32) STAGE_KV((t0 + 3) & 3, t0 + 3);

#pragma unroll
        for (int ti = 0; ti < 2; ++ti) {
            const int t = t0 + ti;
            const int cur = t & 3;

            bf16x8 kf[4][2];
#pragma unroll
            for (int si = 0; si < 4; ++si)
#pragma unroll
                for (int kd = 0; kd < 2; ++kd)
                    kf[si][kd] = *(const bf16x8*)&Kst[cur][(si * 16 + li) * 64 +
                                                           (((kd * 4 + g) ^ (li & 7)) * 8)];

            f32x4 sa[2][4];
#pragma unroll
            for (int mi = 0; mi < 2; ++mi)
#pragma unroll
                for (int si = 0; si < 4; ++si) sa[mi][si] = (f32x4){0.f, 0.f, 0.f, 0.f};
            __builtin_amdgcn_s_setprio(1);
#pragma unroll
            for (int mi = 0; mi < 2; ++mi)
#pragma unroll
                for (int si = 0; si < 4; ++si)
#pragma unroll
                    for (int kd = 0; kd < 2; ++kd)
                        sa[mi][si] = __builtin_amdgcn_mfma_f32_16x16x32_bf16(qf[mi][kd], kf[si][kd],
                                                                             sa[mi][si], 0, 0, 0);
            __builtin_amdgcn_s_setprio(0);

            bf16x8 vf[2][4];
#pragma unroll
            for (int sblk = 0; sblk < 2; ++sblk)
#pragma unroll
                for (int ni = 0; ni < 4; ++ni)
                    vf[sblk][ni] = *(const bf16x8*)&Vst[cur][(ni * 16 + li) * 64 +
                                                             (((sblk * 4 + g) ^ (li & 7)) * 8)];

#pragma unroll
            for (int mi = 0; mi < 2; ++mi)
#pragma unroll
                for (int r = 0; r < 4; ++r) {
                    float ps = 0.f;
#pragma unroll
                    for (int si = 0; si < 4; ++si) {
                        const float p = fast_exp2(sa[mi][si][r]);
                        sa[mi][si][r] = p;
                        ps += p;
                    }
                    lrow[mi][r] += ps;
                }

#pragma unroll
            for (int mi = 0; mi < 2; ++mi)
#pragma unroll
                for (int si = 0; si < 4; ++si)
#pragma unroll
                    for (int r = 0; r < 4; ++r) {
                        const int row = mi * 16 + g * 4 + r;
                        const int col = (si * 16 + li) ^ (((row >> 2) & 3) << 4);
                        pl[row * 64 + col] = bf16_rn(sa[mi][si][r]);
                    }

            asm volatile("s_waitcnt lgkmcnt(0)" ::: "memory");
            __builtin_amdgcn_sched_barrier(0);  // rule #18: pin ops after the wait

            bf16x8 pa[2][2];
#pragma unroll
            for (int mi = 0; mi < 2; ++mi)
#pragma unroll
                for (int sblk = 0; sblk < 2; ++sblk) {
                    const int row = mi * 16 + li;
                    const int e = (sblk * 32 + g * 8) ^ (((row >> 2) & 3) << 4);
                    pa[mi][sblk] = *(const bf16x8*)&pl[row * 64 + e];
                }

            __builtin_amdgcn_s_setprio(1);
#pragma unroll
            for (int sblk = 0; sblk < 2; ++sblk)
#pragma unroll
                for (int ni = 0; ni < 4; ++ni)
#pragma unroll
                    for (int mi = 0; mi < 2; ++mi)
                        o[mi][ni] = __builtin_amdgcn_mfma_f32_16x16x32_bf16(
                            pa[mi][sblk], vf[sblk][ni], o[mi][ni], 0, 0, 0);
            __builtin_amdgcn_s_setprio(0);
        }
    }

    // ---- tail: 32 memory tokens (global reads, no LDS staging) ----
    {
        bf16x8 kf[2][2];
#pragma unroll
        for (int si = 0; si < 2; ++si)
#pragma unroll
            for (int kd = 0; kd < 2; ++kd)
                kf[si][kd] = *(const bf16x8*)(mk + (size_t)(si * 16 + li) * 1024 + h * 64 +
                                              kd * 32 + g * 8);
        bf16x8 vf[4];
#pragma unroll
        for (int ni = 0; ni < 4; ++ni)
            vf[ni] = *(const bf16x8*)(vth + (size_t)(ni * 16 + li) * 2080 + 2048 + g * 8);

        f32x4 sa[2][2];
#pragma unroll
        for (int mi = 0; mi < 2; ++mi)
#pragma unroll
            for (int si = 0; si < 2; ++si) sa[mi][si] = (f32x4){0.f, 0.f, 0.f, 0.f};
#pragma unroll
        for (int mi = 0; mi < 2; ++mi)
#pragma unroll
            for (int si = 0; si < 2; ++si)
#pragma unroll
                for (int kd = 0; kd < 2; ++kd)
                    sa[mi][si] = __builtin_amdgcn_mfma_f32_16x16x32_bf16(qf[mi][kd], kf[si][kd],
                                                                         sa[mi][si], 0, 0, 0);
#pragma unroll
        for (int mi = 0; mi < 2; ++mi)
#pragma unroll
            for (int r = 0; r < 4; ++r) {
                float ps = 0.f;
#pragma unroll
                for (int si = 0; si < 2; ++si) {
                    const float p = fast_exp2(sa[mi][si][r]);
                    sa[mi][si][r] = p;
                    ps += p;
                }
                lrow[mi][r] += ps;
            }
#pragma unroll
        for (int mi = 0; mi < 2; ++mi)
#pragma unroll
            for (int si = 0; si < 2; ++si)
#pragma unroll
                for (int r = 0; r < 4; ++r) {
                    const int row = mi * 16 + g * 4 + r;
                    const int col = (si * 16 + li) ^ (((row >> 2) & 3) << 4);
                    pl[row * 64 + col] = bf16_rn(sa[mi][si][r]);
                }

        asm volatile("s_waitcnt lgkmcnt(0)" ::: "memory");
        __builtin_amdgcn_sched_barrier(0);

        bf16x8 pa[2];
#pragma unroll
        for (int mi = 0; mi < 2; ++mi) {
            const int row = mi * 16 + li;
            const int e = (g * 8) ^ (((row >> 2) & 3) << 4);
            pa[mi] = *(const bf16x8*)&pl[row * 64 + e];
        }
#pragma unroll
        for (int ni = 0; ni < 4; ++ni)
#pragma unroll
            for (int mi = 0; mi < 2; ++mi)
                o[mi][ni] = __builtin_amdgcn_mfma_f32_16x16x32_bf16(pa[mi], vf[ni], o[mi][ni], 0, 0, 0);
    }

    // epilogue: one shuffle-reduce of the deferred row sums, then scatter
#pragma unroll
    for (int mi = 0; mi < 2; ++mi)
#pragma unroll
        for (int r = 0; r < 4; ++r) {
            float s = lrow[mi][r];
#pragma unroll
            for (int d = 1; d < 16; d <<= 1) s += __shfl_xor(s, d);
            const float inv = 1.f / s;
            const int trow = q0 + mi * 16 + g * 4 + r;
#pragma unroll
            for (int ni = 0; ni < 4; ++ni)
                ctx[(size_t)(trow * 2 + b) * 1024 + h * 64 + ni * 16 + li] =
                    bf16_rn(o[mi][ni][r] * inv);
        }
#undef STAGE_KV
}

// ---------------- LayerNorm over rows of 1024: y = LN(p0+p1+p2+p3 + res) ----------------
// pbase: 4 bf16 split-K partials at stride 4096*1024 (p0 carries the bias).
// Residual: resf (fp32) or resb (bf16) — exactly one non-null.
__global__ __launch_bounds__(256, 4) void ln_sum_kernel(
    const bf16* __restrict__ pbase, const float* __restrict__ resf,
    const bf16* __restrict__ resb, const float* __restrict__ gw, const float* __restrict__ bw,
    float* __restrict__ y, bf16* __restrict__ ybf) {
    const int row = blockIdx.x;
    const int tid = threadIdx.x;
    const size_t base = (size_t)row * 1024 + tid * 4;
    const size_t PS = (size_t)4096 * 1024;

    float4 v = {0.f, 0.f, 0.f, 0.f};
#pragma unroll
    for (int z = 0; z < 4; ++z) {
        const bf16x4 a = *(const bf16x4*)(pbase + z * PS + base);
        v.x += bf2f(a[0]);
        v.y += bf2f(a[1]);
        v.z += bf2f(a[2]);
        v.w += bf2f(a[3]);
    }
    if (resf) {
        const float4 xr = ((const float4*)(resf + (size_t)row * 1024))[tid];
        v.x += xr.x; v.y += xr.y; v.z += xr.z; v.w += xr.w;
    } else {
        const bf16x4 xr = *(const bf16x4*)(resb + base);
        v.x += bf2f(xr[0]); v.y += bf2f(xr[1]); v.z += bf2f(xr[2]); v.w += bf2f(xr[3]);
    }

    float s = v.x + v.y + v.z + v.w;
    float s2 = v.x * v.x + v.y * v.y + v.z * v.z + v.w * v.w;
#pragma unroll
    for (int d = 1; d < 64; d <<= 1) {
        s += __shfl_xor(s, d);
        s2 += __shfl_xor(s2, d);
    }
    __shared__ float red[8];
    const int wid = tid >> 6, lane = tid & 63;
    if (lane == 0) { red[wid] = s; red[4 + wid] = s2; }
    __syncthreads();
    s = red[0] + red[1] + red[2] + red[3];
    s2 = red[4] + red[5] + red[6] + red[7];
    const float mu = s * (1.f / 1024.f);
    const float var = s2 * (1.f / 1024.f) - mu * mu;
    const float rstd = rsqrtf(var + 1e-5f);
    const float4 gv = ((const float4*)gw)[tid];
    const float4 bv = ((const float4*)bw)[tid];
    float4 out;
    out.x = (v.x - mu) * rstd * gv.x + bv.x;
    out.y = (v.y - mu) * rstd * gv.y + bv.y;
    out.z = (v.z - mu) * rstd * gv.z + bv.z;
    out.w = (v.w - mu) * rstd * gv.w + bv.w;
    if (y) ((float4*)(y + (size_t)row * 1024))[tid] = out;
    if (ybf) {
        bf16* yb = ybf + base;
        yb[0] = bf16_rn(out.x);
        yb[1] = bf16_rn(out.y);
        yb[2] = bf16_rn(out.z);
        yb[3] = bf16_rn(out.w);
    }
}

// ---------------- fused fp32 -> bf16 for all 7 inputs (one launch) ----------------
// f4-cumulative segment bounds (src, inproj_w, outw, w1, w2, memk, memv):
//   1048576, 1835008, 2097152, 3145728, 4194304, 4202496, 4210688 (= 16448*256 exactly)
__global__ void cvt_all_kernel(const float* __restrict__ s0, const float* __restrict__ s1,
                               const float* __restrict__ s2, const float* __restrict__ s3,
                               const float* __restrict__ s4, const float* __restrict__ s5,
                               const float* __restrict__ s6, bf16* __restrict__ d0,
                               bf16* __restrict__ d1, bf16* __restrict__ d2, bf16* __restrict__ d3,
                               bf16* __restrict__ d4, bf16* __restrict__ d5, bf16* __restrict__ d6) {
    int i = blockIdx.x * 256 + threadIdx.x;
    const float* in;
    bf16* out;
    float scale = 1.f;
    if (i < 1048576) {
        in = s0; out = d0;
    } else if (i < 1835008) {
        in = s1; out = d1; i -= 1048576;
    } else if (i < 2097152) {
        in = s2; out = d2; i -= 1835008;
    } else if (i < 3145728) {
        in = s3; out = d3; i -= 2097152;
    } else if (i < 4194304) {
        in = s4; out = d4; i -= 3145728;
    } else if (i < 4202496) {
        in = s5; out = d5; i -= 4194304; scale = 8.f;  // memk * d^0.5 (log2e rides on q)
    } else {
        in = s6; out = d6; i -= 4202496; scale = 5.656854249492381f;  // memv * M^0.5
    }
    const float4 v = ((const float4*)in)[i];
    bf16* op = out + (size_t)i * 4;
    op[0] = bf16_rn(v.x * scale);
    op[1] = bf16_rn(v.y * scale);
    op[2] = bf16_rn(v.z * scale);
    op[3] = bf16_rn(v.w * scale);
}

extern "C" void kernel_launch(void* const* d_in, const int* in_sizes, int n_in, void* d_out,
                              int out_size, void* d_ws, size_t ws_size, hipStream_t stream) {
    const float* src = (const float*)d_in[0];
    const float* inproj_w = (const float*)d_in[1];
    const float* inproj_b = (const float*)d_in[2];
    const float* outw = (const float*)d_in[3];
    const float* outb = (const float*)d_in[4];
    const float* memk = (const float*)d_in[5];
    const float* memv = (const float*)d_in[6];
    const float* w1 = (const float*)d_in[7];
    const float* b1 = (const float*)d_in[8];
    const float* w2 = (const float*)d_in[9];
    const float* b2 = (const float*)d_in[10];
    const float* ln1g = (const float*)d_in[11];
    const float* ln1b = (const float*)d_in[12];
    const float* ln2g = (const float*)d_in[13];
    const float* ln2b = (const float*)d_in[14];

    char* ws = (char*)d_ws;
    const size_t MB = 1024 * 1024;
    // Live-range plan (ws <= 97 MB):
    //   0..24   weights bf16 (inproj 6 | outw 2 | w1 8 | w2 8)
    //   24..25  mk_bf, mv_bf
    //   25..33  src_bf -> ctx (attn out) -> x_bf (ln1 out)
    //   33..65  qkv (gemm1 out) -> gemm2 partials (qkv dead) -> h (gemm3 out)
    //   65..97  vt (8.5MB, transpose_v -> attn) -> gemm4 partials (vt dead)
    bf16* w_inproj_bf = (bf16*)(ws + 0);
    bf16* w_out_bf = (bf16*)(ws + 6 * MB);
    bf16* w1_bf = (bf16*)(ws + 8 * MB);
    bf16* w2_bf = (bf16*)(ws + 16 * MB);
    bf16* mk_bf = (bf16*)(ws + 24 * MB);
    bf16* mv_bf = (bf16*)(ws + 24 * MB + 65536);
    bf16* src_bf = (bf16*)(ws + 25 * MB);
    bf16* ctx_bf = src_bf;     // attn out (src_bf dead after gemm1)
    bf16* x_bf = src_bf;       // ln1 out (ctx dead after gemm2)
    bf16* qkv_bf = (bf16*)(ws + 33 * MB);
    bf16* g2p = qkv_bf;        // gemm2 partials 4x8MB (qkv dead after attn)
    bf16* h_bf = qkv_bf;       // gemm3 out (partials dead after ln_sum1)
    bf16* vt_bf = (bf16*)(ws + 65 * MB);
    bf16* g4p = vt_bf;         // gemm4 partials 4x8MB (vt dead after attn)
    float* outp = (float*)d_out;

    // one fused conversion launch (16448 * 256 threads == total f4 count exactly)
    cvt_all_kernel<<<dim3(16448), dim3(256), 0, stream>>>(
        src, inproj_w, outw, w1, w2, memk, memv,
        src_bf, w_inproj_bf, w_out_bf, w1_bf, w2_bf, mk_bf, mv_bf);

    // qkv = src @ in_proj_w^T + b  (q scaled by d^-0.5*log2e)
    gemm_bt<0><<<dim3(3072 / 128, 4096 / 128), 256, 0, stream>>>(
        src_bf, w_inproj_bf, inproj_b, qkv_bf, 4096, 3072, 1024, 1024);
    // VT = V^T (incl. mem tokens)
    transpose_v<<<dim3(33, 16, 2), 256, 0, stream>>>(qkv_bf, mv_bf, vt_bf);
    // ctx = softmax(q k^T) v    (grid: x=head for XCD L2 locality; 512 blocks)
    attn_kernel<<<dim3(16, 16, 2), 256, 0, stream>>>(qkv_bf, mk_bf, vt_bf, ctx_bf);
    // gemm2 split-K x4: partials = ctx @ out_w^T (+out_b on z=0), K=256 each
    gemm_bt<3><<<dim3(1024 / 128, 4096 / 128, 4), 256, 0, stream>>>(
        ctx_bf, w_out_bf, outb, g2p, 4096, 1024, 256, 1024);
    // x = LN1(p0..p3 + src)  -> bf16 only
    ln_sum_kernel<<<dim3(4096), 256, 0, stream>>>(g2p, src, nullptr, ln1g, ln1b, nullptr, x_bf);
    // h = relu(x @ w1^T + b1)
    gemm_bt<2><<<dim3(4096 / 128, 4096 / 128), 256, 0, stream>>>(
        x_bf, w1_bf, b1, h_bf, 4096, 4096, 1024, 1024);
    // gemm4 split-K x4: partials = h @ w2^T (+b2 on z=0), K=1024 each
    gemm_bt<3><<<dim3(1024 / 128, 4096 / 128, 4), 256, 0, stream>>>(
        h_bf, w2_bf, b2, g4p, 4096, 1024, 1024, 4096);
    // out = LN2(p0..p3 + x)
    ln_sum_kernel<<<dim3(4096), 256, 0, stream>>>(g4p, nullptr, x_bf, ln2g, ln2b, outp, nullptr);
}

// Round 16
// 225.769 us; speedup vs baseline: 1.1225x; 1.0269x over previous
//
#include <hip/hip_runtime.h>
#include <hip/hip_bf16.h>
#include <cstdint>

// Pipeline (all bf16 MFMA, fp32 accum):
//   cvt_all -> gemm1(qkv) -> transpose_v -> attn(flash, 32x32 swapped-QK^T, in-register P)
//   -> gemm2(split-K x4, bf16 partials) -> ln_sum1(+src) -> gemm3(relu)
//   -> gemm4(split-K x4, bf16 partials) -> ln_sum2(+x_bf)
// Round-16: attn P-LDS roundtrip eliminated (T12). Swapped QK^T via
// mfma_f32_32x32x16_bf16 puts q = lane&31 for every S^T value -> PV A-operand
// assembled in-register with cvt_pk_bf16 + v_permlane32_swap_b32 (mapping
// verified element-wise; lanes l/l^32 share q and split k, one shfl_xor(32)
// finishes row sums). No lgkmcnt drain, no Plds (LDS 80->64KB).
// Ring staging/grid and all other kernels byte-identical to round 15.

using bf16 = __hip_bfloat16;
typedef __attribute__((ext_vector_type(8))) __bf16 bf16x8;
typedef __attribute__((ext_vector_type(4))) __bf16 bf16x4;
typedef __attribute__((ext_vector_type(4))) float f32x4;
typedef __attribute__((ext_vector_type(16))) float f32x16;

__device__ __forceinline__ void gload_lds16(const void* g, void* l) {
    auto gp = (const __attribute__((address_space(1))) void*)(uintptr_t)g;
    auto lp = (__attribute__((address_space(3))) void*)(uint32_t)(uintptr_t)l;
    __builtin_amdgcn_global_load_lds(gp, lp, 16, 0, 0);
}

// raw v_exp_f32 (1 instr) — scores are small/finite, no guard path needed
__device__ __forceinline__ float fast_exp2(float x) {
#if __has_builtin(__builtin_amdgcn_exp2f)
    return __builtin_amdgcn_exp2f(x);
#else
    float r;
    asm("v_exp_f32 %0, %1" : "=v"(r) : "v"(x));
    return r;
#endif
}

// 2-instr f32->bf16 (round-to-nearest). Inputs finite; bias far below threshold.
__device__ __forceinline__ bf16 bf16_rn(float x) {
    uint32_t u = __builtin_bit_cast(uint32_t, x);
    uint16_t h = (uint16_t)((u + 0x8000u) >> 16);
    return __builtin_bit_cast(bf16, h);
}

__device__ __forceinline__ float bf2f(__bf16 x) {
    return (float)x;
}

// pack two f32 -> u32 of 2 bf16 (lo = a, hi = b)
__device__ __forceinline__ unsigned cvt_pk_bf16(float a, float b) {
    unsigned r;
    asm("v_cvt_pk_bf16_f32 %0, %1, %2" : "=v"(r) : "v"(a), "v"(b));
    return r;
}

// v_permlane32_swap_b32: new_a[l>=32] = old_b[l-32]; new_b[l<32] = old_a[l+32]
__device__ __forceinline__ void pl32swap(unsigned& a, unsigned& b) {
    asm volatile("v_permlane32_swap_b32 %0, %1" : "+v"(a), "+v"(b));
}

// ---------------- GEMM: C[M,N] = A[M,K] * B[N,K]^T (+bias, epilogue) ----------------
// EPI 0: qkv -> bf16, cols < 1024 scaled by d^-0.5 * log2(e)
// EPI 2: bf16 out = relu(acc + bias)
// EPI 3: split-K partial (gridDim.z=Z): slice z covers K columns [z*K, z*K+K) of
//        A/B (row stride lda), writes bf16 partial to Cb + z*M*N; z=0 adds bias.
template <int EPI>
__global__ __launch_bounds__(256, 2) void gemm_bt(
    const bf16* __restrict__ A, const bf16* __restrict__ B,
    const float* __restrict__ bias, bf16* __restrict__ Cb,
    int M, int N, int K, int lda) {
    __shared__ alignas(16) bf16 As[128 * 32];
    __shared__ alignas(16) bf16 Bs[128 * 32];

    const int tid = threadIdx.x;
    const int wid = tid >> 6;
    const int lane = tid & 63;
    const int g = lane >> 4;
    const int li = lane & 15;

    if (EPI == 3) {
        const int zo = blockIdx.z * K;
        A += zo;
        B += zo;
    }

    // XCD-aware bijective swizzle (all grids here have nwg % 8 == 0)
    int wg = blockIdx.y * gridDim.x + blockIdx.x;
    const int nwg = gridDim.x * gridDim.y;
    const int cpx = nwg >> 3;
    wg = (wg & 7) * cpx + (wg >> 3);
    const int bx = wg % (int)gridDim.x;
    const int by = wg / (int)gridDim.x;

    const int row0 = by * 128;
    const int col0 = bx * 128;
    const int wr = (wid >> 1) * 64;
    const int wc = (wid & 1) * 64;

    const int c0 = wid, c1 = wid + 4;
    const int srow = lane >> 2;
    const int scol = (lane & 3) * 8;

    const bf16* Ag0 = A + (size_t)(row0 + c0 * 16 + srow) * lda + scol;
    const bf16* Ag1 = A + (size_t)(row0 + c1 * 16 + srow) * lda + scol;
    const bf16* Bg0 = B + (size_t)(col0 + c0 * 16 + srow) * lda + scol;
    const bf16* Bg1 = B + (size_t)(col0 + c1 * 16 + srow) * lda + scol;

    bf16* lA0 = &As[c0 * 512];
    bf16* lA1 = &As[c1 * 512];
    bf16* lB0 = &Bs[c0 * 512];
    bf16* lB1 = &Bs[c1 * 512];

    f32x4 acc[4][4];
#pragma unroll
    for (int i = 0; i < 4; ++i)
#pragma unroll
        for (int j = 0; j < 4; ++j) acc[i][j] = (f32x4){0.f, 0.f, 0.f, 0.f};

    for (int k0 = 0; k0 < K; k0 += 32) {
        gload_lds16(Ag0 + k0, lA0);
        gload_lds16(Ag1 + k0, lA1);
        gload_lds16(Bg0 + k0, lB0);
        gload_lds16(Bg1 + k0, lB1);
        __syncthreads();

        bf16x8 af[4], bfr[4];
#pragma unroll
        for (int i = 0; i < 4; ++i) {
            af[i] = *(const bf16x8*)&As[(wr + i * 16 + li) * 32 + g * 8];
            bfr[i] = *(const bf16x8*)&Bs[(wc + i * 16 + li) * 32 + g * 8];
        }
#pragma unroll
        for (int i = 0; i < 4; ++i)
#pragma unroll
            for (int j = 0; j < 4; ++j)
                acc[i][j] = __builtin_amdgcn_mfma_f32_16x16x32_bf16(af[i], bfr[j], acc[i][j], 0, 0, 0);
        __syncthreads();
    }

#pragma unroll
    for (int i = 0; i < 4; ++i) {
#pragma unroll
        for (int j = 0; j < 4; ++j) {
            const int col = col0 + wc + j * 16 + li;
            const float bv = (EPI == 3 && blockIdx.z != 0) ? 0.f : bias[col];
#pragma unroll
            for (int r = 0; r < 4; ++r) {
                const int row = row0 + wr + i * 16 + g * 4 + r;
                const size_t idx = (size_t)row * N + col;
                float v = acc[i][j][r] + bv;
                if (EPI == 0) {
                    if (col < 1024) v *= 0.18033688011112042f;  // d^-0.5 * log2(e)
                    Cb[idx] = bf16_rn(v);
                } else if (EPI == 2) {
                    Cb[idx] = bf16_rn(v > 0.f ? v : 0.f);
                } else {  // EPI == 3
                    Cb[(size_t)blockIdx.z * ((size_t)M * N) + idx] = bf16_rn(v);
                }
            }
        }
    }
}

// ---------------- V transpose: VT[(b*16+h)*64 + d][s] for s in [0,2080) ----------------
__global__ __launch_bounds__(256) void transpose_v(const bf16* __restrict__ qkv,
                                                   const bf16* __restrict__ mv,
                                                   bf16* __restrict__ vt) {
    __shared__ bf16 tile[64][72];
    const int t = blockIdx.x;  // 0..32 (32 = mem-token tile, 32 rows)
    const int h = blockIdx.y;
    const int b = blockIdx.z;
    const int tid = threadIdx.x;
    const int r = tid >> 2;
    const int c = (tid & 3) * 16;
    const int s0 = t * 64;
    if (t < 32) {
        const bf16* p = qkv + (size_t)((s0 + r) * 2 + b) * 3072 + 2048 + h * 64 + c;
        *(bf16x8*)&tile[r][c] = *(const bf16x8*)p;
        *(bf16x8*)&tile[r][c + 8] = *(const bf16x8*)(p + 8);
    } else if (r < 32) {
        const bf16* p = mv + (size_t)r * 1024 + h * 64 + c;
        *(bf16x8*)&tile[r][c] = *(const bf16x8*)p;
        *(bf16x8*)&tile[r][c + 8] = *(const bf16x8*)(p + 8);
    }
    __syncthreads();
    const int d = tid >> 2;
    const int sc = (tid & 3) * 16;
    const int smax = (t < 32) ? 64 : 32;
    if (sc < smax) {
        bf16 tmp[16];
#pragma unroll
        for (int j = 0; j < 16; ++j) tmp[j] = tile[sc + j][d];
        bf16* q = vt + (size_t)((b * 16 + h) * 64 + d) * 2080 + s0 + sc;
        *(bf16x8*)q = *(const bf16x8*)&tmp[0];
        *(bf16x8*)(q + 8) = *(const bf16x8*)&tmp[8];
    }
}

// ---------------- flash attention (32x32 swapped-QK^T, in-register P) ----------------
// Block = 4 waves x 32 q-rows. Grid (h, qtile, b): x=16 % 8 == 0 -> all blocks of
// head h share XCD h%8, K/V L2-resident. K/V staged per block into a 4-slot ring,
// __syncthreads every 2 tiles (round-15 structure).
// Swapped QK^T: S^T = mfma32x32(K_frag, Q_frag) -> lane(hh,l31) holds
// P[q=l31][k = kb*32 + (r&3)+8*(r>>2)+4*hh]. PV A-frags assembled in-register:
// pk[kb][m]=cvt_pk(p[2m],p[2m+1]); per k-chunk kc: pl32swap(pk[b],pk[b+2]) and
// pl32swap(pk[b+1],pk[b+3]) give words W0..W3. Lanes l/l^32 share q and split k;
// shfl_xor(lrow,32) completes row sums; epilogue shfl redistributes 1/sum.
__global__ __launch_bounds__(256, 2) void attn_kernel(
    const bf16* __restrict__ qkv, const bf16* __restrict__ mk,
    const bf16* __restrict__ vt, bf16* __restrict__ ctx) {
    __shared__ alignas(16) bf16 Kst[4][64 * 64];
    __shared__ alignas(16) bf16 Vst[4][64 * 64];

    const int tid = threadIdx.x;
    const int wid = tid >> 6;
    const int lane = tid & 63;
    const int l31 = lane & 31;
    const int hh = lane >> 5;
    const int l7 = lane & 7;

    const int h = blockIdx.x;
    const int b = blockIdx.z;
    const int q0 = blockIdx.y * 128 + wid * 32;

    const bf16* vth = vt + (size_t)((b * 16 + h) * 64) * 2080;

    const int srow8 = lane >> 3;           // row & 7
    const int sslot = (lane & 7) ^ srow8;  // swizzled 16B slot in the row

#define STAGE_KV(buf, t)                                                                       \
    {                                                                                          \
        const int _s0 = (t) * 64;                                                              \
        _Pragma("unroll") for (int j = 0; j < 2; ++j) {                                        \
            const int rw = (wid * 2 + j) * 8 + srow8;                                          \
            gload_lds16(qkv + (size_t)((_s0 + rw) * 2 + b) * 3072 + 1024 + h * 64 + sslot * 8, \
                        &Kst[buf][(wid * 2 + j) * 512]);                                       \
            gload_lds16(vth + (size_t)rw * 2080 + _s0 + sslot * 8,                             \
                        &Vst[buf][(wid * 2 + j) * 512]);                                       \
        }                                                                                      \
    }

    // Q as 32x32 B-operand: qf[dc] = Q[q0+l31][h*64 + dc*16 + hh*8 .. +7]
    bf16x8 qf[4];
#pragma unroll
    for (int dc = 0; dc < 4; ++dc)
        qf[dc] = *(const bf16x8*)(qkv + (size_t)((q0 + l31) * 2 + b) * 3072 + h * 64 + dc * 16 +
                                  hh * 8);

    f32x16 zero16;
#pragma unroll
    for (int i = 0; i < 16; ++i) zero16[i] = 0.f;

    f32x16 o[2];
    o[0] = zero16;
    o[1] = zero16;
    float lrow = 0.f;

    STAGE_KV(0, 0);
    STAGE_KV(1, 1);

    for (int tp = 0; tp < 16; ++tp) {
        const int t0 = tp * 2;
        __syncthreads();  // ring slots staged; prior readers done
        if (t0 + 2 < 32) STAGE_KV((t0 + 2) & 3, t0 + 2);
        if (t0 + 3 < 32) STAGE_KV((t0 + 3) & 3, t0 + 3);

#pragma unroll
        for (int ti = 0; ti < 2; ++ti) {
            const int cur = (t0 + ti) & 3;
            const bf16* kbase = &Kst[cur][0];
            const bf16* vbase = &Vst[cur][0];

            // S^T = K * Q^T over d=64 (4 chunks of 16), two 32-k halves
            f32x16 sa[2];
            sa[0] = zero16;
            sa[1] = zero16;
            __builtin_amdgcn_s_setprio(1);
#pragma unroll
            for (int dc = 0; dc < 4; ++dc)
#pragma unroll
                for (int kb = 0; kb < 2; ++kb) {
                    const int row = kb * 32 + l31;
                    const bf16x8 ka =
                        *(const bf16x8*)&kbase[row * 64 + (((dc * 2 + hh) ^ l7) * 8)];
                    sa[kb] = __builtin_amdgcn_mfma_f32_32x32x16_bf16(ka, qf[dc], sa[kb], 0, 0, 0);
                }
            __builtin_amdgcn_s_setprio(0);

            // exp2 + per-lane row-sum (q = l31) + pack to bf16 pairs
            unsigned pk[2][8];
#pragma unroll
            for (int kb = 0; kb < 2; ++kb)
#pragma unroll
                for (int m = 0; m < 8; ++m) {
                    const float p0 = fast_exp2(sa[kb][2 * m]);
                    const float p1 = fast_exp2(sa[kb][2 * m + 1]);
                    lrow += p0 + p1;
                    pk[kb][m] = cvt_pk_bf16(p0, p1);
                }

            // PV: per 16-k chunk, assemble A-frag via 2 permlane swaps
            __builtin_amdgcn_s_setprio(1);
#pragma unroll
            for (int kc = 0; kc < 4; ++kc) {
                const int kb = kc >> 1;
                const int base = (kc & 1) * 4;
                unsigned A0 = pk[kb][base], A1 = pk[kb][base + 2];
                unsigned B0 = pk[kb][base + 1], B1 = pk[kb][base + 3];
                pl32swap(A0, A1);
                pl32swap(B0, B1);
                union {
                    unsigned u[4];
                    bf16x8 v;
                } pa;
                pa.u[0] = A0;
                pa.u[1] = B0;
                pa.u[2] = A1;
                pa.u[3] = B1;
#pragma unroll
                for (int dt = 0; dt < 2; ++dt) {
                    const int row = dt * 32 + l31;
                    const bf16x8 vb =
                        *(const bf16x8*)&vbase[row * 64 + (((kc * 2 + hh) ^ l7) * 8)];
                    o[dt] = __builtin_amdgcn_mfma_f32_32x32x16_bf16(pa.v, vb, o[dt], 0, 0, 0);
                }
            }
            __builtin_amdgcn_s_setprio(0);
        }
    }

    // ---- tail: 32 memory tokens (global reads, no LDS staging) ----
    {
        f32x16 sat = zero16;
#pragma unroll
        for (int dc = 0; dc < 4; ++dc) {
            const bf16x8 ka =
                *(const bf16x8*)(mk + (size_t)l31 * 1024 + h * 64 + dc * 16 + hh * 8);
            sat = __builtin_amdgcn_mfma_f32_32x32x16_bf16(ka, qf[dc], sat, 0, 0, 0);
        }
        unsigned pkt[8];
#pragma unroll
        for (int m = 0; m < 8; ++m) {
            const float p0 = fast_exp2(sat[2 * m]);
            const float p1 = fast_exp2(sat[2 * m + 1]);
            lrow += p0 + p1;
            pkt[m] = cvt_pk_bf16(p0, p1);
        }
#pragma unroll
        for (int kc = 0; kc < 2; ++kc) {
            const int base = kc * 4;
            unsigned A0 = pkt[base], A1 = pkt[base + 2];
            unsigned B0 = pkt[base + 1], B1 = pkt[base + 3];
            pl32swap(A0, A1);
            pl32swap(B0, B1);
            union {
                unsigned u[4];
                bf16x8 v;
            } pa;
            pa.u[0] = A0;
            pa.u[1] = B0;
            pa.u[2] = A1;
            pa.u[3] = B1;
#pragma unroll
            for (int dt = 0; dt < 2; ++dt) {
                const bf16x8 vb = *(const bf16x8*)(vth + (size_t)(dt * 32 + l31) * 2080 + 2048 +
                                                   kc * 16 + hh * 8);
                o[dt] = __builtin_amdgcn_mfma_f32_32x32x16_bf16(pa.v, vb, o[dt], 0, 0, 0);
            }
        }
    }

    // epilogue: lanes l and l^32 share q=l31 and split k — combine, then
    // redistribute 1/sum to the lanes holding each output row.
    const float ssum = lrow + __shfl_xor(lrow, 32);
    const float inv_own = 1.f / ssum;
#pragma unroll
    for (int r = 0; r < 16; ++r) {
        const int qr = (r & 3) + 8 * (r >> 2) + 4 * hh;
        const float iv = __shfl(inv_own, qr);
#pragma unroll
        for (int dt = 0; dt < 2; ++dt)
            ctx[(size_t)((q0 + qr) * 2 + b) * 1024 + h * 64 + dt * 32 + l31] =
                bf16_rn(o[dt][r] * iv);
    }
#undef STAGE_KV
}

// ---------------- LayerNorm over rows of 1024: y = LN(p0+p1+p2+p3 + res) ----------------
// pbase: 4 bf16 split-K partials at stride 4096*1024 (p0 carries the bias).
// Residual: resf (fp32) or resb (bf16) — exactly one non-null.
__global__ __launch_bounds__(256, 4) void ln_sum_kernel(
    const bf16* __restrict__ pbase, const float* __restrict__ resf,
    const bf16* __restrict__ resb, const float* __restrict__ gw, const float* __restrict__ bw,
    float* __restrict__ y, bf16* __restrict__ ybf) {
    const int row = blockIdx.x;
    const int tid = threadIdx.x;
    const size_t base = (size_t)row * 1024 + tid * 4;
    const size_t PS = (size_t)4096 * 1024;

    float4 v = {0.f, 0.f, 0.f, 0.f};
#pragma unroll
    for (int z = 0; z < 4; ++z) {
        const bf16x4 a = *(const bf16x4*)(pbase + z * PS + base);
        v.x += bf2f(a[0]);
        v.y += bf2f(a[1]);
        v.z += bf2f(a[2]);
        v.w += bf2f(a[3]);
    }
    if (resf) {
        const float4 xr = ((const float4*)(resf + (size_t)row * 1024))[tid];
        v.x += xr.x; v.y += xr.y; v.z += xr.z; v.w += xr.w;
    } else {
        const bf16x4 xr = *(const bf16x4*)(resb + base);
        v.x += bf2f(xr[0]); v.y += bf2f(xr[1]); v.z += bf2f(xr[2]); v.w += bf2f(xr[3]);
    }

    float s = v.x + v.y + v.z + v.w;
    float s2 = v.x * v.x + v.y * v.y + v.z * v.z + v.w * v.w;
#pragma unroll
    for (int d = 1; d < 64; d <<= 1) {
        s += __shfl_xor(s, d);
        s2 += __shfl_xor(s2, d);
    }
    __shared__ float red[8];
    const int wid = tid >> 6, lane = tid & 63;
    if (lane == 0) { red[wid] = s; red[4 + wid] = s2; }
    __syncthreads();
    s = red[0] + red[1] + red[2] + red[3];
    s2 = red[4] + red[5] + red[6] + red[7];
    const float mu = s * (1.f / 1024.f);
    const float var = s2 * (1.f / 1024.f) - mu * mu;
    const float rstd = rsqrtf(var + 1e-5f);
    const float4 gv = ((const float4*)gw)[tid];
    const float4 bv = ((const float4*)bw)[tid];
    float4 out;
    out.x = (v.x - mu) * rstd * gv.x + bv.x;
    out.y = (v.y - mu) * rstd * gv.y + bv.y;
    out.z = (v.z - mu) * rstd * gv.z + bv.z;
    out.w = (v.w - mu) * rstd * gv.w + bv.w;
    if (y) ((float4*)(y + (size_t)row * 1024))[tid] = out;
    if (ybf) {
        bf16* yb = ybf + base;
        yb[0] = bf16_rn(out.x);
        yb[1] = bf16_rn(out.y);
        yb[2] = bf16_rn(out.z);
        yb[3] = bf16_rn(out.w);
    }
}

// ---------------- fused fp32 -> bf16 for all 7 inputs (one launch) ----------------
// f4-cumulative segment bounds (src, inproj_w, outw, w1, w2, memk, memv):
//   1048576, 1835008, 2097152, 3145728, 4194304, 4202496, 4210688 (= 16448*256 exactly)
__global__ void cvt_all_kernel(const float* __restrict__ s0, const float* __restrict__ s1,
                               const float* __restrict__ s2, const float* __restrict__ s3,
                               const float* __restrict__ s4, const float* __restrict__ s5,
                               const float* __restrict__ s6, bf16* __restrict__ d0,
                               bf16* __restrict__ d1, bf16* __restrict__ d2, bf16* __restrict__ d3,
                               bf16* __restrict__ d4, bf16* __restrict__ d5, bf16* __restrict__ d6) {
    int i = blockIdx.x * 256 + threadIdx.x;
    const float* in;
    bf16* out;
    float scale = 1.f;
    if (i < 1048576) {
        in = s0; out = d0;
    } else if (i < 1835008) {
        in = s1; out = d1; i -= 1048576;
    } else if (i < 2097152) {
        in = s2; out = d2; i -= 1835008;
    } else if (i < 3145728) {
        in = s3; out = d3; i -= 2097152;
    } else if (i < 4194304) {
        in = s4; out = d4; i -= 3145728;
    } else if (i < 4202496) {
        in = s5; out = d5; i -= 4194304; scale = 8.f;  // memk * d^0.5 (log2e rides on q)
    } else {
        in = s6; out = d6; i -= 4202496; scale = 5.656854249492381f;  // memv * M^0.5
    }
    const float4 v = ((const float4*)in)[i];
    bf16* op = out + (size_t)i * 4;
    op[0] = bf16_rn(v.x * scale);
    op[1] = bf16_rn(v.y * scale);
    op[2] = bf16_rn(v.z * scale);
    op[3] = bf16_rn(v.w * scale);
}

extern "C" void kernel_launch(void* const* d_in, const int* in_sizes, int n_in, void* d_out,
                              int out_size, void* d_ws, size_t ws_size, hipStream_t stream) {
    const float* src = (const float*)d_in[0];
    const float* inproj_w = (const float*)d_in[1];
    const float* inproj_b = (const float*)d_in[2];
    const float* outw = (const float*)d_in[3];
    const float* outb = (const float*)d_in[4];
    const float* memk = (const float*)d_in[5];
    const float* memv = (const float*)d_in[6];
    const float* w1 = (const float*)d_in[7];
    const float* b1 = (const float*)d_in[8];
    const float* w2 = (const float*)d_in[9];
    const float* b2 = (const float*)d_in[10];
    const float* ln1g = (const float*)d_in[11];
    const float* ln1b = (const float*)d_in[12];
    const float* ln2g = (const float*)d_in[13];
    const float* ln2b = (const float*)d_in[14];

    char* ws = (char*)d_ws;
    const size_t MB = 1024 * 1024;
    // Live-range plan (ws <= 97 MB):
    //   0..24   weights bf16 (inproj 6 | outw 2 | w1 8 | w2 8)
    //   24..25  mk_bf, mv_bf
    //   25..33  src_bf -> ctx (attn out) -> x_bf (ln1 out)
    //   33..65  qkv (gemm1 out) -> gemm2 partials (qkv dead) -> h (gemm3 out)
    //   65..97  vt (8.5MB, transpose_v -> attn) -> gemm4 partials (vt dead)
    bf16* w_inproj_bf = (bf16*)(ws + 0);
    bf16* w_out_bf = (bf16*)(ws + 6 * MB);
    bf16* w1_bf = (bf16*)(ws + 8 * MB);
    bf16* w2_bf = (bf16*)(ws + 16 * MB);
    bf16* mk_bf = (bf16*)(ws + 24 * MB);
    bf16* mv_bf = (bf16*)(ws + 24 * MB + 65536);
    bf16* src_bf = (bf16*)(ws + 25 * MB);
    bf16* ctx_bf = src_bf;     // attn out (src_bf dead after gemm1)
    bf16* x_bf = src_bf;       // ln1 out (ctx dead after gemm2)
    bf16* qkv_bf = (bf16*)(ws + 33 * MB);
    bf16* g2p = qkv_bf;        // gemm2 partials 4x8MB (qkv dead after attn)
    bf16* h_bf = qkv_bf;       // gemm3 out (partials dead after ln_sum1)
    bf16* vt_bf = (bf16*)(ws + 65 * MB);
    bf16* g4p = vt_bf;         // gemm4 partials 4x8MB (vt dead after attn)
    float* outp = (float*)d_out;

    // one fused conversion launch (16448 * 256 threads == total f4 count exactly)
    cvt_all_kernel<<<dim3(16448), dim3(256), 0, stream>>>(
        src, inproj_w, outw, w1, w2, memk, memv,
        src_bf, w_inproj_bf, w_out_bf, w1_bf, w2_bf, mk_bf, mv_bf);

    // qkv = src @ in_proj_w^T + b  (q scaled by d^-0.5*log2e)
    gemm_bt<0><<<dim3(3072 / 128, 4096 / 128), 256, 0, stream>>>(
        src_bf, w_inproj_bf, inproj_b, qkv_bf, 4096, 3072, 1024, 1024);
    // VT = V^T (incl. mem tokens)
    transpose_v<<<dim3(33, 16, 2), 256, 0, stream>>>(qkv_bf, mv_bf, vt_bf);
    // ctx = softmax(q k^T) v    (grid: x=head for XCD L2 locality; 512 blocks)
    attn_kernel<<<dim3(16, 16, 2), 256, 0, stream>>>(qkv_bf, mk_bf, vt_bf, ctx_bf);
    // gemm2 split-K x4: partials = ctx @ out_w^T (+out_b on z=0), K=256 each
    gemm_bt<3><<<dim3(1024 / 128, 4096 / 128, 4), 256, 0, stream>>>(
        ctx_bf, w_out_bf, outb, g2p, 4096, 1024, 256, 1024);
    // x = LN1(p0..p3 + src)  -> bf16 only
    ln_sum_kernel<<<dim3(4096), 256, 0, stream>>>(g2p, src, nullptr, ln1g, ln1b, nullptr, x_bf);
    // h = relu(x @ w1^T + b1)
    gemm_bt<2><<<dim3(4096 / 128, 4096 / 128), 256, 0, stream>>>(
        x_bf, w1_bf, b1, h_bf, 4096, 4096, 1024, 1024);
    // gemm4 split-K x4: partials = h @ w2^T (+b2 on z=0), K=1024 each
    gemm_bt<3><<<dim3(1024 / 128, 4096 / 128, 4), 256, 0, stream>>>(
        h_bf, w2_bf, b2, g4p, 4096, 1024, 1024, 4096);
    // out = LN2(p0..p3 + x)
    ln_sum_kernel<<<dim3(4096), 256, 0, stream>>>(g4p, nullptr, x_bf, ln2g, ln2b, outp, nullptr);
}